// Round 1
// baseline (592.319 us; speedup 1.0000x reference)
//
#include <hip/hip_runtime.h>
#include <cstdint>
#include <cmath>

typedef unsigned short u16;
typedef unsigned int   u32;
typedef short bf16x8 __attribute__((ext_vector_type(8)));
typedef float f32x4  __attribute__((ext_vector_type(4)));

#define MFMA16(a, b, c) __builtin_amdgcn_mfma_f32_16x16x32_bf16((a), (b), (c), 0, 0, 0)

__device__ __forceinline__ u16 f2b(float f) {
  u32 u = __float_as_uint(f);
  return (u16)((u + 0x7FFFu + ((u >> 16) & 1u)) >> 16);
}
__device__ __forceinline__ float b2f(u16 h) {
  return __uint_as_float(((u32)h) << 16);
}
__device__ __forceinline__ void async16(const void* g, void* l) {
  __builtin_amdgcn_global_load_lds((const __attribute__((address_space(1))) u32*)g,
                                   (__attribute__((address_space(3))) u32*)l, 16, 0, 0);
}

// ---------------- prep: split x into bf16 hi/lo ----------------
__global__ void split_x_kernel(const float* __restrict__ x, u16* __restrict__ hi,
                               u16* __restrict__ lo, int n4) {
  int i = blockIdx.x * blockDim.x + threadIdx.x;
  if (i >= n4) return;
  float4 v = reinterpret_cast<const float4*>(x)[i];
  u16 h0 = f2b(v.x), h1 = f2b(v.y), h2 = f2b(v.z), h3 = f2b(v.w);
  u16 l0 = f2b(v.x - b2f(h0)), l1 = f2b(v.y - b2f(h1));
  u16 l2 = f2b(v.z - b2f(h2)), l3 = f2b(v.w - b2f(h3));
  uint2 hp, lp;
  hp.x = (u32)h0 | ((u32)h1 << 16); hp.y = (u32)h2 | ((u32)h3 << 16);
  lp.x = (u32)l0 | ((u32)l1 << 16); lp.y = (u32)l2 | ((u32)l3 << 16);
  reinterpret_cast<uint2*>(hi)[i] = hp;
  reinterpret_cast<uint2*>(lo)[i] = lp;
}

// ---------------- prep: transpose weight [K,N] f32 -> [N][K] bf16 hi/lo ----------------
__global__ void wtrans_kernel(const float* __restrict__ W, int N,
                              u16* __restrict__ Thi, u16* __restrict__ Tlo,
                              int row_off, int dst_ld) {
  __shared__ float tile[32][33];
  int k0 = blockIdx.x * 32, n0 = blockIdx.y * 32;
  int tx = threadIdx.x & 31, ty = threadIdx.x >> 5;  // 32 x 8
#pragma unroll
  for (int i = 0; i < 32; i += 8)
    tile[ty + i][tx] = W[(size_t)(k0 + ty + i) * N + n0 + tx];
  __syncthreads();
#pragma unroll
  for (int i = 0; i < 32; i += 8) {
    float v = tile[tx][ty + i];
    size_t o = (size_t)(row_off + n0 + ty + i) * dst_ld + k0 + tx;
    u16 h = f2b(v);
    Thi[o] = h;
    Tlo[o] = f2b(v - b2f(h));
  }
}

// ---------------- generic 3-term bf16x3 GEMM ----------------
// C[M,N] = (Ahi+Alo)[M,K] @ (Bhi+Blo)^T-stored-[N,K] + bias
// MODE 0: f32 out (ldc). MODE 1: bf16 hi/lo pair out (ldc). MODE 2: bf16 to
// [b,h,s,128] head layout (q_c/k_c halves).
template <int MODE>
__global__ __launch_bounds__(256, 2) void gemm3_kernel(
    const u16* __restrict__ Ahi, const u16* __restrict__ Alo, int lda,
    const u16* __restrict__ Bhi, const u16* __restrict__ Blo, int ldb,
    const float* __restrict__ bias, const float* __restrict__ bias2, int bsplit,
    void* __restrict__ out0, void* __restrict__ out1, int N, int K, int ldc) {
  __shared__ u16 lA[2][128 * 64];
  __shared__ u16 lB[2][128 * 64];
  const int tid = threadIdx.x;
  const int wave = tid >> 6, lane = tid & 63;
  const int lrow = lane & 15, kgrp = lane >> 4;
  const int bm = blockIdx.x * 128, bn = blockIdx.y * 128;
  const int wm = (wave >> 1) * 64, wn = (wave & 1) * 64;
  const int srow = lane >> 3, sg = lane & 7;

  f32x4 acc[4][4];
  const f32x4 zero = {0.f, 0.f, 0.f, 0.f};
#pragma unroll
  for (int i = 0; i < 4; ++i)
#pragma unroll
    for (int j = 0; j < 4; ++j) acc[i][j] = zero;

  for (int kt = 0; kt < K; kt += 64) {
#pragma unroll
    for (int ii = 0; ii < 4; ++ii) {
      int inst = wave * 4 + ii;
      int row = inst * 8 + srow;                 // 0..127
      int koff = kt + ((sg ^ (row & 7)) << 3);   // pre-swizzled source granule
      async16(Ahi + (size_t)(bm + row) * lda + koff, &lA[0][inst * 512]);
      async16(Alo + (size_t)(bm + row) * lda + koff, &lA[1][inst * 512]);
      int brow = bn + row;
      if (brow > N - 1) brow = N - 1;
      async16(Bhi + (size_t)brow * ldb + koff, &lB[0][inst * 512]);
      async16(Blo + (size_t)brow * ldb + koff, &lB[1][inst * 512]);
    }
    asm volatile("s_waitcnt vmcnt(0)" ::: "memory");
    __syncthreads();

#pragma unroll
    for (int ks = 0; ks < 2; ++ks) {
      bf16x8 ah[4], al[4], bhv[4], blv[4];
#pragma unroll
      for (int mi = 0; mi < 4; ++mi) {
        int row = wm + mi * 16 + lrow;
        int off = row * 128 + ((ks * 64 + kgrp * 16) ^ ((row & 7) << 4));
        ah[mi] = *(const bf16x8*)((const char*)lA[0] + off);
        al[mi] = *(const bf16x8*)((const char*)lA[1] + off);
      }
#pragma unroll
      for (int ni = 0; ni < 4; ++ni) {
        int row = wn + ni * 16 + lrow;
        int off = row * 128 + ((ks * 64 + kgrp * 16) ^ ((row & 7) << 4));
        bhv[ni] = *(const bf16x8*)((const char*)lB[0] + off);
        blv[ni] = *(const bf16x8*)((const char*)lB[1] + off);
      }
#pragma unroll
      for (int mi = 0; mi < 4; ++mi)
#pragma unroll
        for (int ni = 0; ni < 4; ++ni) {
          acc[mi][ni] = MFMA16(ah[mi], bhv[ni], acc[mi][ni]);
          acc[mi][ni] = MFMA16(ah[mi], blv[ni], acc[mi][ni]);
          acc[mi][ni] = MFMA16(al[mi], bhv[ni], acc[mi][ni]);
        }
    }
    __syncthreads();
  }

#pragma unroll
  for (int mi = 0; mi < 4; ++mi) {
#pragma unroll
    for (int ni = 0; ni < 4; ++ni) {
      int col = bn + wn + ni * 16 + lrow;
      if (col >= N) continue;
      float bv = (col < bsplit) ? bias[col] : bias2[col - bsplit];
      int row0 = bm + wm + mi * 16 + kgrp * 4;
#pragma unroll
      for (int r = 0; r < 4; ++r) {
        int row = row0 + r;
        float v = acc[mi][ni][r] + bv;
        if (MODE == 0) {
          ((float*)out0)[(size_t)row * ldc + col] = v;
        } else if (MODE == 1) {
          u16 h = f2b(v);
          ((u16*)out0)[(size_t)row * ldc + col] = h;
          ((u16*)out1)[(size_t)row * ldc + col] = f2b(v - b2f(h));
        } else {
          int bb = row >> 9, ss = row & 511, hh = col >> 6, dd = col & 63;
          ((u16*)out0)[(((size_t)(bb * 16 + hh) * 512 + ss) << 7) + dd] = f2b(v);
        }
      }
    }
  }
}

// ---------------- rope on q_r -> Qb[...,64:128] ----------------
__global__ void ropeq_kernel(const float* __restrict__ qr, u16* __restrict__ Qb) {
  int idx = blockIdx.x * 256 + threadIdx.x;  // 8192*512
  int t = idx >> 9;
  int rem = idx & 511;
  int h = rem >> 5, i = rem & 31;
  float2 v = reinterpret_cast<const float2*>(qr + (size_t)t * 1024 + h * 64)[i];
  float theta = exp2f((float)i * (-13.287712379549449f / 32.0f));  // 10000^(-i/32)
  float ang = (float)(t & 511) * theta;
  float sn = sinf(ang), cs = cosf(ang);
  // reference has swapped names: cos_pos=sin(.), sin_pos=cos(.)
  float o0 = v.x * sn - v.y * cs;
  float o1 = v.y * sn + v.x * cs;
  size_t o = ((size_t)((t >> 9) * 16 + h) * 512 + (t & 511)) * 128 + 64 + 2 * i;
  u32 pk = (u32)f2b(o0) | ((u32)f2b(o1) << 16);
  *reinterpret_cast<u32*>(Qb + o) = pk;
}

// ---------------- rope on k_r -> broadcast into Kb[...,64:128] ----------------
__global__ void ropek_kernel(const float* __restrict__ kr, u16* __restrict__ Kb) {
  int idx = blockIdx.x * 256 + threadIdx.x;  // 8192*32
  int t = idx >> 5, i = idx & 31;
  float2 v = reinterpret_cast<const float2*>(kr + (size_t)t * 64)[i];
  float theta = exp2f((float)i * (-13.287712379549449f / 32.0f));
  float ang = (float)(t & 511) * theta;
  float sn = sinf(ang), cs = cosf(ang);
  float o0 = v.x * sn - v.y * cs;
  float o1 = v.y * sn + v.x * cs;
  u32 pk = (u32)f2b(o0) | ((u32)f2b(o1) << 16);
  int bb = t >> 9, ss = t & 511;
  size_t base = (size_t)bb * 16 * 512 * 128;
#pragma unroll
  for (int hh = 0; hh < 16; ++hh)
    *reinterpret_cast<u32*>(Kb + base + ((size_t)(hh * 512 + ss)) * 128 + 64 + 2 * i) = pk;
}

// ---------------- transpose v [8192,1024]f32 -> Vt [bh][64][512] bf16 ----------------
__global__ void vtrans_kernel(const float* __restrict__ v, u16* __restrict__ Vt) {
  __shared__ u16 tl[64][65];
  const int bh = blockIdx.x, b = bh >> 4, h = bh & 15;
  const int s0 = blockIdx.y * 64;
  const int tid = threadIdx.x;
  const int d = tid & 63, si = tid >> 6;
#pragma unroll
  for (int i = 0; i < 64; i += 4)
    tl[si + i][d] = f2b(v[((size_t)(b * 512 + s0 + si + i)) * 1024 + h * 64 + d]);
  __syncthreads();
  const int sj = tid & 63, dd = tid >> 6;
#pragma unroll
  for (int i = 0; i < 64; i += 4)
    Vt[((size_t)bh * 64 + dd + i) * 512 + s0 + sj] = tl[sj][dd + i];
}

// ---------------- fused flash attention per (b,h, 64-row q tile) ----------------
__global__ __launch_bounds__(256, 2) void attn_kernel(
    const u16* __restrict__ Qb, const u16* __restrict__ Kb, const u16* __restrict__ Vt,
    const int* __restrict__ mask, u16* __restrict__ ctx_hi, u16* __restrict__ ctx_lo,
    float scale) {
  __shared__ u16 sQ[64 * 128];
  __shared__ u16 sK[64 * 128];
  __shared__ u16 sV[64 * 64];
  __shared__ u16 sP[4][16 * 64];
  const int tid = threadIdx.x, wave = tid >> 6, lane = tid & 63;
  const int lrow = lane & 15, kgrp = lane >> 4;
  const int bh = blockIdx.x, b = bh >> 4, h = bh & 15;
  const int q0 = blockIdx.y * 64;
  const size_t qkbase = (size_t)bh * 512 * 128;
  const size_t vbase = (size_t)bh * 64 * 512;

  {  // stage Q tile once (rows 256B = 16 granules, xor-swizzled source)
    int g = lane & 15, rr = lane >> 4;
#pragma unroll
    for (int ii = 0; ii < 4; ++ii) {
      int inst = wave * 4 + ii;
      int row = inst * 4 + rr;
      int perm = (g & 8) | ((g & 7) ^ (row & 7));
      async16(Qb + qkbase + (size_t)(q0 + row) * 128 + perm * 8, &sQ[inst * 512]);
    }
  }

  const f32x4 zero = {0.f, 0.f, 0.f, 0.f};
  f32x4 O[4];
#pragma unroll
  for (int nf = 0; nf < 4; ++nf) O[nf] = zero;
  float m_run[4], l_run[4];
#pragma unroll
  for (int r = 0; r < 4; ++r) { m_run[r] = -1e30f; l_run[r] = 0.f; }

  for (int kvt = 0; kvt < 8; ++kvt) {
    const int kv0 = kvt * 64;
    {
      int g = lane & 15, rr = lane >> 4;
#pragma unroll
      for (int ii = 0; ii < 4; ++ii) {
        int inst = wave * 4 + ii;
        int row = inst * 4 + rr;
        int perm = (g & 8) | ((g & 7) ^ (row & 7));
        async16(Kb + qkbase + (size_t)(kv0 + row) * 128 + perm * 8, &sK[inst * 512]);
      }
      int g2 = lane & 7, r2 = lane >> 3;
#pragma unroll
      for (int ii = 0; ii < 2; ++ii) {
        int inst = wave * 2 + ii;
        int row = inst * 8 + r2;
        async16(Vt + vbase + (size_t)row * 512 + kv0 + ((g2 ^ (row & 7)) << 3),
                &sV[inst * 512]);
      }
    }
    asm volatile("s_waitcnt vmcnt(0)" ::: "memory");
    __syncthreads();

    f32x4 S[4];
#pragma unroll
    for (int nf = 0; nf < 4; ++nf) S[nf] = zero;
#pragma unroll
    for (int ks = 0; ks < 4; ++ks) {
      int qrow = wave * 16 + lrow;
      int kb = ks * 64 + kgrp * 16;
      bf16x8 aq = *(const bf16x8*)((const char*)sQ + qrow * 256 + (kb ^ ((qrow & 7) << 4)));
#pragma unroll
      for (int nf = 0; nf < 4; ++nf) {
        int krow = nf * 16 + lrow;
        bf16x8 bk = *(const bf16x8*)((const char*)sK + krow * 256 + (kb ^ ((krow & 7) << 4)));
        S[nf] = MFMA16(aq, bk, S[nf]);
      }
    }

    float pvv[4][4];
    float tmax[4] = {-1e30f, -1e30f, -1e30f, -1e30f};
#pragma unroll
    for (int nf = 0; nf < 4; ++nf) {
      int mk = mask[b * 512 + kv0 + nf * 16 + lrow];
#pragma unroll
      for (int r = 0; r < 4; ++r) {
        float v = (mk != 0) ? S[nf][r] * scale : -1e30f;
        pvv[nf][r] = v;
        tmax[r] = fmaxf(tmax[r], v);
      }
    }
#pragma unroll
    for (int r = 0; r < 4; ++r) {
#pragma unroll
      for (int mv = 1; mv < 16; mv <<= 1)
        tmax[r] = fmaxf(tmax[r], __shfl_xor(tmax[r], mv, 64));
    }
#pragma unroll
    for (int r = 0; r < 4; ++r) {
      float newm = fmaxf(m_run[r], tmax[r]);
      float sc = expf(m_run[r] - newm);
      float ts = 0.f;
      int qp = kgrp * 4 + r;
#pragma unroll
      for (int nf = 0; nf < 4; ++nf) {
        float pe = expf(pvv[nf][r] - newm);
        u16 hb = f2b(pe);
        int c = nf * 16 + lrow;
        sP[wave][(qp * 64 + c) ^ ((qp & 7) << 3)] = hb;
        ts += b2f(hb);
      }
#pragma unroll
      for (int mv = 1; mv < 16; mv <<= 1) ts += __shfl_xor(ts, mv, 64);
      l_run[r] = l_run[r] * sc + ts;
      m_run[r] = newm;
#pragma unroll
      for (int nf = 0; nf < 4; ++nf) O[nf][r] *= sc;
    }

#pragma unroll
    for (int ks = 0; ks < 2; ++ks) {
      int kb = ks * 64 + kgrp * 16;
      bf16x8 ap = *(const bf16x8*)((const char*)sP[wave] + ((lrow * 128 + kb) ^ ((lrow & 7) << 4)));
#pragma unroll
      for (int nf = 0; nf < 4; ++nf) {
        int vr = nf * 16 + lrow;
        bf16x8 bv = *(const bf16x8*)((const char*)sV + vr * 128 + (kb ^ ((vr & 7) << 4)));
        O[nf] = MFMA16(ap, bv, O[nf]);
      }
    }
    __syncthreads();
  }

#pragma unroll
  for (int r = 0; r < 4; ++r) {
    float inv = 1.0f / l_run[r];
    int trow = b * 512 + q0 + wave * 16 + kgrp * 4 + r;
#pragma unroll
    for (int nf = 0; nf < 4; ++nf) {
      int col = h * 64 + nf * 16 + lrow;
      float v = O[nf][r] * inv;
      u16 hb = f2b(v);
      ctx_hi[(size_t)trow * 1024 + col] = hb;
      ctx_lo[(size_t)trow * 1024 + col] = f2b(v - b2f(hb));
    }
  }
}

// ---------------- launch ----------------
extern "C" void kernel_launch(void* const* d_in, const int* in_sizes, int n_in,
                              void* d_out, int out_size, void* d_ws, size_t ws_size,
                              hipStream_t stream) {
  const float* x     = (const float*)d_in[0];
  const int*   mask  = (const int*)d_in[1];
  const float* w_dkv = (const float*)d_in[2];
  const float* b_dkv = (const float*)d_in[3];
  const float* w_dq  = (const float*)d_in[4];
  const float* b_dq  = (const float*)d_in[5];
  const float* w_uq  = (const float*)d_in[6];
  const float* b_uq  = (const float*)d_in[7];
  const float* w_uk  = (const float*)d_in[8];
  const float* b_uk  = (const float*)d_in[9];
  const float* w_uv  = (const float*)d_in[10];
  const float* b_uv  = (const float*)d_in[11];
  const float* w_qr  = (const float*)d_in[12];
  const float* b_qr  = (const float*)d_in[13];
  const float* w_kr  = (const float*)d_in[14];
  const float* b_kr  = (const float*)d_in[15];
  const float* w_fc  = (const float*)d_in[16];
  const float* b_fc  = (const float*)d_in[17];
  float* out = (float*)d_out;

  char* ws = (char*)d_ws;
  size_t off = 0;
  auto alloc = [&](size_t bytes) -> void* {
    void* p = ws + off;
    off += (bytes + 255) & ~(size_t)255;
    return p;
  };
  u16* xhi   = (u16*)alloc(33554432);   // 8192x2048 bf16 (later reused as qr_f32)
  u16* xlo   = (u16*)alloc(33554432);   // (later reused as v_f32)
  u16* WfTh  = (u16*)alloc(4194304);    // [1024][2048]
  u16* WfTl  = (u16*)alloc(4194304);
  u16* WuqTh = (u16*)alloc(1048576);    // [1024][512]
  u16* WuqTl = (u16*)alloc(1048576);
  u16* WqrTh = (u16*)alloc(1048576);
  u16* WqrTl = (u16*)alloc(1048576);
  u16* WukTh = (u16*)alloc(1048576);
  u16* WukTl = (u16*)alloc(1048576);
  u16* WuvTh = (u16*)alloc(1048576);
  u16* WuvTl = (u16*)alloc(1048576);
  u16* WkrTh = (u16*)alloc(65536);      // [64][512]
  u16* WkrTl = (u16*)alloc(65536);
  u16* WfcTh = (u16*)alloc(4194304);    // [2048][1024]
  u16* WfcTl = (u16*)alloc(4194304);
  u16* chi   = (u16*)alloc(16777216);   // c = [ckv|cq] [8192][1024] (reused as ctx)
  u16* clo   = (u16*)alloc(16777216);
  u16* Qb    = (u16*)alloc(33554432);   // [256][512][128]
  u16* Kb    = (u16*)alloc(33554432);
  u16* Vt    = (u16*)alloc(16777216);   // [256][64][512]
  float* krf = (float*)alloc(2097152);  // [8192][64]
  float* qrf = (float*)xhi;             // [8192][1024] (aliases dead xhi)
  float* vf  = (float*)xlo;             // [8192][1024] (aliases dead xlo)
  u16* ctxh = chi;                      // attention output aliases dead c
  u16* ctxl = clo;
  (void)ws_size; (void)in_sizes; (void)n_in; (void)out_size;

  const float scale = 1.0f / (sqrtf(128.0f) + sqrtf(64.0f));

  split_x_kernel<<<16384, 256, 0, stream>>>(x, xhi, xlo, 4194304);
  wtrans_kernel<<<dim3(64, 16), 256, 0, stream>>>(w_dkv, 512, WfTh, WfTl, 0, 2048);
  wtrans_kernel<<<dim3(64, 16), 256, 0, stream>>>(w_dq, 512, WfTh, WfTl, 512, 2048);
  wtrans_kernel<<<dim3(16, 32), 256, 0, stream>>>(w_uq, 1024, WuqTh, WuqTl, 0, 512);
  wtrans_kernel<<<dim3(16, 32), 256, 0, stream>>>(w_qr, 1024, WqrTh, WqrTl, 0, 512);
  wtrans_kernel<<<dim3(16, 32), 256, 0, stream>>>(w_uk, 1024, WukTh, WukTl, 0, 512);
  wtrans_kernel<<<dim3(16, 32), 256, 0, stream>>>(w_uv, 1024, WuvTh, WuvTl, 0, 512);
  wtrans_kernel<<<dim3(16, 2), 256, 0, stream>>>(w_kr, 64, WkrTh, WkrTl, 0, 512);
  wtrans_kernel<<<dim3(32, 64), 256, 0, stream>>>(w_fc, 2048, WfcTh, WfcTl, 0, 1024);

  // c = x @ [w_dkv | w_dq] + [b_dkv | b_dq]   -> hi/lo bf16 [8192][1024]
  gemm3_kernel<1><<<dim3(64, 8), 256, 0, stream>>>(
      xhi, xlo, 2048, WfTh, WfTl, 2048, b_dkv, b_dq, 512,
      (void*)chi, (void*)clo, 1024, 2048, 1024);
  // q_c = c_q @ w_uq -> Qb head layout
  gemm3_kernel<2><<<dim3(64, 8), 256, 0, stream>>>(
      chi + 512, clo + 512, 1024, WuqTh, WuqTl, 512, b_uq, b_uq, 1024,
      (void*)Qb, nullptr, 1024, 512, 0);
  // q_r pre-rope -> f32
  gemm3_kernel<0><<<dim3(64, 8), 256, 0, stream>>>(
      chi + 512, clo + 512, 1024, WqrTh, WqrTl, 512, b_qr, b_qr, 1024,
      (void*)qrf, nullptr, 1024, 512, 1024);
  // k_c = c_kv @ w_uk -> Kb head layout
  gemm3_kernel<2><<<dim3(64, 8), 256, 0, stream>>>(
      chi, clo, 1024, WukTh, WukTl, 512, b_uk, b_uk, 1024,
      (void*)Kb, nullptr, 1024, 512, 0);
  // v = c_kv @ w_uv -> f32
  gemm3_kernel<0><<<dim3(64, 8), 256, 0, stream>>>(
      chi, clo, 1024, WuvTh, WuvTl, 512, b_uv, b_uv, 1024,
      (void*)vf, nullptr, 1024, 512, 1024);
  // k_r pre-rope -> f32 (N=64)
  gemm3_kernel<0><<<dim3(64, 1), 256, 0, stream>>>(
      chi, clo, 1024, WkrTh, WkrTl, 512, b_kr, b_kr, 64,
      (void*)krf, nullptr, 64, 512, 64);

  ropeq_kernel<<<16384, 256, 0, stream>>>(qrf, Qb);
  ropek_kernel<<<1024, 256, 0, stream>>>(krf, Kb);
  vtrans_kernel<<<dim3(256, 8), 256, 0, stream>>>(vf, Vt);

  attn_kernel<<<dim3(256, 8), 256, 0, stream>>>(Qb, Kb, Vt, mask, ctxh, ctxl, scale);

  // out = ctx @ w_fc + b_fc  -> f32 [8192][2048]
  gemm3_kernel<0><<<dim3(64, 16), 256, 0, stream>>>(
      ctxh, ctxl, 1024, WfcTh, WfcTl, 1024, b_fc, b_fc, 2048,
      (void*)out, nullptr, 2048, 1024, 2048);
}

// Round 2
// 563.710 us; speedup vs baseline: 1.0508x; 1.0508x over previous
//
#include <hip/hip_runtime.h>
#include <cstdint>
#include <cmath>

typedef unsigned short u16;
typedef unsigned int   u32;
typedef short bf16x8 __attribute__((ext_vector_type(8)));
typedef float f32x4  __attribute__((ext_vector_type(4)));

#define MFMA16(a, b, c) __builtin_amdgcn_mfma_f32_16x16x32_bf16((a), (b), (c), 0, 0, 0)

__device__ __forceinline__ u16 f2b(float f) {
  u32 u = __float_as_uint(f);
  return (u16)((u + 0x7FFFu + ((u >> 16) & 1u)) >> 16);
}
__device__ __forceinline__ float b2f(u16 h) {
  return __uint_as_float(((u32)h) << 16);
}
__device__ __forceinline__ float fexp2(float x) { return __builtin_amdgcn_exp2f(x); }
__device__ __forceinline__ void async16(const void* g, void* l) {
  __builtin_amdgcn_global_load_lds((const __attribute__((address_space(1))) u32*)g,
                                   (__attribute__((address_space(3))) u32*)l, 16, 0, 0);
}

// ---------------- prep: split x into bf16 hi/lo ----------------
__global__ void split_x_kernel(const float* __restrict__ x, u16* __restrict__ hi,
                               u16* __restrict__ lo, int n4) {
  int i = blockIdx.x * blockDim.x + threadIdx.x;
  if (i >= n4) return;
  float4 v = reinterpret_cast<const float4*>(x)[i];
  u16 h0 = f2b(v.x), h1 = f2b(v.y), h2 = f2b(v.z), h3 = f2b(v.w);
  u16 l0 = f2b(v.x - b2f(h0)), l1 = f2b(v.y - b2f(h1));
  u16 l2 = f2b(v.z - b2f(h2)), l3 = f2b(v.w - b2f(h3));
  uint2 hp, lp;
  hp.x = (u32)h0 | ((u32)h1 << 16); hp.y = (u32)h2 | ((u32)h3 << 16);
  lp.x = (u32)l0 | ((u32)l1 << 16); lp.y = (u32)l2 | ((u32)l3 << 16);
  reinterpret_cast<uint2*>(hi)[i] = hp;
  reinterpret_cast<uint2*>(lo)[i] = lp;
}

// ---------------- prep: transpose weight [K,N] f32 -> [N][K] bf16 hi/lo ----------------
__global__ void wtrans_kernel(const float* __restrict__ W, int N,
                              u16* __restrict__ Thi, u16* __restrict__ Tlo,
                              int row_off, int dst_ld) {
  __shared__ float tile[32][33];
  int k0 = blockIdx.x * 32, n0 = blockIdx.y * 32;
  int tx = threadIdx.x & 31, ty = threadIdx.x >> 5;  // 32 x 8
#pragma unroll
  for (int i = 0; i < 32; i += 8)
    tile[ty + i][tx] = W[(size_t)(k0 + ty + i) * N + n0 + tx];
  __syncthreads();
#pragma unroll
  for (int i = 0; i < 32; i += 8) {
    float v = tile[tx][ty + i];
    size_t o = (size_t)(row_off + n0 + ty + i) * dst_ld + k0 + tx;
    u16 h = f2b(v);
    Thi[o] = h;
    Tlo[o] = f2b(v - b2f(h));
  }
}

// ---------------- generic bf16 multi-term GEMM ----------------
// C[M,N] = A[M,K] @ B^T-stored-[N,K] + bias
// TERMS==3: A split hi/lo, terms ah*bh + ah*bl + al*bh
// TERMS==2: A single bf16,  terms a*bh + a*bl
// MODE 0: f32 out. MODE 2: bf16 to [b,h,s,128] head layout. MODE 3: bf16 out.
template <int MODE, int TERMS>
__global__ __launch_bounds__(256, 2) void gemm3_kernel(
    const u16* __restrict__ Ahi, const u16* __restrict__ Alo, int lda,
    const u16* __restrict__ Bhi, const u16* __restrict__ Blo, int ldb,
    const float* __restrict__ bias, const float* __restrict__ bias2, int bsplit,
    void* __restrict__ out0, void* __restrict__ out1, int N, int K, int ldc) {
  constexpr int ABUF = (TERMS == 3) ? 2 : 1;
  __shared__ u16 lA[ABUF][128 * 64];
  __shared__ u16 lB[2][128 * 64];
  const int tid = threadIdx.x;
  const int wave = tid >> 6, lane = tid & 63;
  const int lrow = lane & 15, kgrp = lane >> 4;
  // bijective XCD-aware swizzle (all grids are multiples of 8)
  const int nwg = gridDim.x * gridDim.y;
  const int orig = blockIdx.y * gridDim.x + blockIdx.x;
  const int swz = (orig & 7) * (nwg >> 3) + (orig >> 3);
  const int bm = (swz % gridDim.x) * 128, bn = (swz / gridDim.x) * 128;
  const int wm = (wave >> 1) * 64, wn = (wave & 1) * 64;
  const int srow = lane >> 3, sg = lane & 7;

  f32x4 acc[4][4];
  const f32x4 zero = {0.f, 0.f, 0.f, 0.f};
#pragma unroll
  for (int i = 0; i < 4; ++i)
#pragma unroll
    for (int j = 0; j < 4; ++j) acc[i][j] = zero;

  for (int kt = 0; kt < K; kt += 64) {
#pragma unroll
    for (int ii = 0; ii < 4; ++ii) {
      int inst = wave * 4 + ii;
      int row = inst * 8 + srow;                 // 0..127
      int koff = kt + ((sg ^ (row & 7)) << 3);   // pre-swizzled source granule
      async16(Ahi + (size_t)(bm + row) * lda + koff, &lA[0][inst * 512]);
      if constexpr (TERMS == 3)
        async16(Alo + (size_t)(bm + row) * lda + koff, &lA[ABUF - 1][inst * 512]);
      int brow = bn + row;
      if (brow > N - 1) brow = N - 1;
      async16(Bhi + (size_t)brow * ldb + koff, &lB[0][inst * 512]);
      async16(Blo + (size_t)brow * ldb + koff, &lB[1][inst * 512]);
    }
    asm volatile("s_waitcnt vmcnt(0)" ::: "memory");
    __syncthreads();

#pragma unroll
    for (int ks = 0; ks < 2; ++ks) {
      bf16x8 ah[4], al[4], bhv[4], blv[4];
#pragma unroll
      for (int mi = 0; mi < 4; ++mi) {
        int row = wm + mi * 16 + lrow;
        int off = row * 128 + ((ks * 64 + kgrp * 16) ^ ((row & 7) << 4));
        ah[mi] = *(const bf16x8*)((const char*)lA[0] + off);
        if constexpr (TERMS == 3)
          al[mi] = *(const bf16x8*)((const char*)lA[ABUF - 1] + off);
      }
#pragma unroll
      for (int ni = 0; ni < 4; ++ni) {
        int row = wn + ni * 16 + lrow;
        int off = row * 128 + ((ks * 64 + kgrp * 16) ^ ((row & 7) << 4));
        bhv[ni] = *(const bf16x8*)((const char*)lB[0] + off);
        blv[ni] = *(const bf16x8*)((const char*)lB[1] + off);
      }
#pragma unroll
      for (int mi = 0; mi < 4; ++mi)
#pragma unroll
        for (int ni = 0; ni < 4; ++ni) {
          acc[mi][ni] = MFMA16(ah[mi], bhv[ni], acc[mi][ni]);
          acc[mi][ni] = MFMA16(ah[mi], blv[ni], acc[mi][ni]);
          if constexpr (TERMS == 3)
            acc[mi][ni] = MFMA16(al[mi], bhv[ni], acc[mi][ni]);
        }
    }
    __syncthreads();
  }

#pragma unroll
  for (int mi = 0; mi < 4; ++mi) {
#pragma unroll
    for (int ni = 0; ni < 4; ++ni) {
      int col = bn + wn + ni * 16 + lrow;
      if (col >= N) continue;
      float bv = (col < bsplit) ? bias[col] : bias2[col - bsplit];
      int row0 = bm + wm + mi * 16 + kgrp * 4;
#pragma unroll
      for (int r = 0; r < 4; ++r) {
        int row = row0 + r;
        float v = acc[mi][ni][r] + bv;
        if (MODE == 0) {
          ((float*)out0)[(size_t)row * ldc + col] = v;
        } else if (MODE == 3) {
          ((u16*)out0)[(size_t)row * ldc + col] = f2b(v);
        } else {
          int bb = row >> 9, ss = row & 511, hh = col >> 6, dd = col & 63;
          ((u16*)out0)[(((size_t)(bb * 16 + hh) * 512 + ss) << 7) + dd] = f2b(v);
        }
      }
    }
  }
}

// ---------------- rope on q_r -> Qb[...,64:128] ----------------
__global__ void ropeq_kernel(const float* __restrict__ qr, u16* __restrict__ Qb) {
  int idx = blockIdx.x * 256 + threadIdx.x;  // 8192*512
  int t = idx >> 9;
  int rem = idx & 511;
  int h = rem >> 5, i = rem & 31;
  float2 v = reinterpret_cast<const float2*>(qr + (size_t)t * 1024 + h * 64)[i];
  float theta = exp2f((float)i * (-13.287712379549449f / 32.0f));  // 10000^(-i/32)
  float ang = (float)(t & 511) * theta;
  float sn = sinf(ang), cs = cosf(ang);
  // reference has swapped names: cos_pos=sin(.), sin_pos=cos(.)
  float o0 = v.x * sn - v.y * cs;
  float o1 = v.y * sn + v.x * cs;
  size_t o = ((size_t)((t >> 9) * 16 + h) * 512 + (t & 511)) * 128 + 64 + 2 * i;
  u32 pk = (u32)f2b(o0) | ((u32)f2b(o1) << 16);
  *reinterpret_cast<u32*>(Qb + o) = pk;
}

// ---------------- rope on k_r -> broadcast into Kb[...,64:128] ----------------
__global__ void ropek_kernel(const float* __restrict__ kr, u16* __restrict__ Kb) {
  int idx = blockIdx.x * 256 + threadIdx.x;  // 8192*32
  int t = idx >> 5, i = idx & 31;
  float2 v = reinterpret_cast<const float2*>(kr + (size_t)t * 64)[i];
  float theta = exp2f((float)i * (-13.287712379549449f / 32.0f));
  float ang = (float)(t & 511) * theta;
  float sn = sinf(ang), cs = cosf(ang);
  float o0 = v.x * sn - v.y * cs;
  float o1 = v.y * sn + v.x * cs;
  u32 pk = (u32)f2b(o0) | ((u32)f2b(o1) << 16);
  int bb = t >> 9, ss = t & 511;
  size_t base = (size_t)bb * 16 * 512 * 128;
#pragma unroll
  for (int hh = 0; hh < 16; ++hh)
    *reinterpret_cast<u32*>(Kb + base + ((size_t)(hh * 512 + ss)) * 128 + 64 + 2 * i) = pk;
}

// ---------------- transpose v [8192,1024]f32 -> Vt [bh][64][512] bf16 ----------------
__global__ void vtrans_kernel(const float* __restrict__ v, u16* __restrict__ Vt) {
  __shared__ u16 tl[64][65];
  const int bh = blockIdx.x, b = bh >> 4, h = bh & 15;
  const int s0 = blockIdx.y * 64;
  const int tid = threadIdx.x;
  const int d = tid & 63, si = tid >> 6;
#pragma unroll
  for (int i = 0; i < 64; i += 4)
    tl[si + i][d] = f2b(v[((size_t)(b * 512 + s0 + si + i)) * 1024 + h * 64 + d]);
  __syncthreads();
  const int sj = tid & 63, dd = tid >> 6;
#pragma unroll
  for (int i = 0; i < 64; i += 4)
    Vt[((size_t)bh * 64 + dd + i) * 512 + s0 + sj] = tl[sj][dd + i];
}

// ---------------- fused flash attention per (b,h, 64-row q tile) ----------------
// logits kept in log2 domain: s' = S*scale*log2e + maskbias
__global__ __launch_bounds__(256, 3) void attn_kernel(
    const u16* __restrict__ Qb, const u16* __restrict__ Kb, const u16* __restrict__ Vt,
    const int* __restrict__ mask, u16* __restrict__ ctx_hi, u16* __restrict__ ctx_lo,
    float scale2) {
  __shared__ u16 sQ[64 * 128];
  __shared__ u16 sK[64 * 128];
  __shared__ u16 sV[64 * 64];
  __shared__ u16 sP[4][16 * 64];
  const int tid = threadIdx.x, wave = tid >> 6, lane = tid & 63;
  const int lrow = lane & 15, kgrp = lane >> 4;
  const int bh = blockIdx.x, b = bh >> 4, h = bh & 15;
  const int q0 = blockIdx.y * 64;
  const size_t qkbase = (size_t)bh * 512 * 128;
  const size_t vbase = (size_t)bh * 64 * 512;
  u16* __restrict__ sPw = sP[wave];

  // loop-invariant P-store offsets (u16-element units)
  u32 poff[4][4];
#pragma unroll
  for (int r = 0; r < 4; ++r) {
    int qp = kgrp * 4 + r;
    int xr = (qp & 7) << 3;
#pragma unroll
    for (int nf = 0; nf < 4; ++nf) poff[r][nf] = (u32)((qp * 64 + nf * 16 + lrow) ^ xr);
  }

  {  // stage Q tile once (rows 256B = 16 granules, xor-swizzled source)
    int g = lane & 15, rr = lane >> 4;
#pragma unroll
    for (int ii = 0; ii < 4; ++ii) {
      int inst = wave * 4 + ii;
      int row = inst * 4 + rr;
      int perm = (g & 8) | ((g & 7) ^ (row & 7));
      async16(Qb + qkbase + (size_t)(q0 + row) * 128 + perm * 8, &sQ[inst * 512]);
    }
  }

  const f32x4 zero = {0.f, 0.f, 0.f, 0.f};
  f32x4 O[4];
#pragma unroll
  for (int nf = 0; nf < 4; ++nf) O[nf] = zero;
  float m_run[4], l_run[4];
#pragma unroll
  for (int r = 0; r < 4; ++r) { m_run[r] = -1e30f; l_run[r] = 0.f; }

  for (int kvt = 0; kvt < 8; ++kvt) {
    const int kv0 = kvt * 64;
    {
      int g = lane & 15, rr = lane >> 4;
#pragma unroll
      for (int ii = 0; ii < 4; ++ii) {
        int inst = wave * 4 + ii;
        int row = inst * 4 + rr;
        int perm = (g & 8) | ((g & 7) ^ (row & 7));
        async16(Kb + qkbase + (size_t)(kv0 + row) * 128 + perm * 8, &sK[inst * 512]);
      }
      int g2 = lane & 7, r2 = lane >> 3;
#pragma unroll
      for (int ii = 0; ii < 2; ++ii) {
        int inst = wave * 2 + ii;
        int row = inst * 8 + r2;
        async16(Vt + vbase + (size_t)row * 512 + kv0 + ((g2 ^ (row & 7)) << 3),
                &sV[inst * 512]);
      }
    }
    // mask -> additive bias while loads are in flight
    float mb[4];
#pragma unroll
    for (int nf = 0; nf < 4; ++nf)
      mb[nf] = (mask[b * 512 + kv0 + nf * 16 + lrow] != 0) ? 0.f : -1e30f;

    asm volatile("s_waitcnt vmcnt(0)" ::: "memory");
    __syncthreads();

    f32x4 S[4];
#pragma unroll
    for (int nf = 0; nf < 4; ++nf) S[nf] = zero;
#pragma unroll
    for (int ks = 0; ks < 4; ++ks) {
      int qrow = wave * 16 + lrow;
      int kb = ks * 64 + kgrp * 16;
      bf16x8 aq = *(const bf16x8*)((const char*)sQ + qrow * 256 + (kb ^ ((qrow & 7) << 4)));
#pragma unroll
      for (int nf = 0; nf < 4; ++nf) {
        int krow = nf * 16 + lrow;
        bf16x8 bk = *(const bf16x8*)((const char*)sK + krow * 256 + (kb ^ ((krow & 7) << 4)));
        S[nf] = MFMA16(aq, bk, S[nf]);
      }
    }

    float pvv[4][4];
    float tmax[4] = {-1e30f, -1e30f, -1e30f, -1e30f};
#pragma unroll
    for (int nf = 0; nf < 4; ++nf) {
#pragma unroll
      for (int r = 0; r < 4; ++r) {
        float v = fmaf(S[nf][r], scale2, mb[nf]);
        pvv[nf][r] = v;
        tmax[r] = fmaxf(tmax[r], v);
      }
    }
#pragma unroll
    for (int r = 0; r < 4; ++r) {
#pragma unroll
      for (int mv = 1; mv < 16; mv <<= 1)
        tmax[r] = fmaxf(tmax[r], __shfl_xor(tmax[r], mv, 64));
    }
#pragma unroll
    for (int r = 0; r < 4; ++r) {
      float newm = fmaxf(m_run[r], tmax[r]);
      float sc = fexp2(m_run[r] - newm);
      m_run[r] = newm;
      float ts = 0.f;
#pragma unroll
      for (int nf = 0; nf < 4; ++nf) {
        float pe = fexp2(pvv[nf][r] - newm);
        sPw[poff[r][nf]] = f2b(pe);
        ts += pe;
      }
#pragma unroll
      for (int mv = 1; mv < 16; mv <<= 1) ts += __shfl_xor(ts, mv, 64);
      l_run[r] = l_run[r] * sc + ts;
#pragma unroll
      for (int nf = 0; nf < 4; ++nf) O[nf][r] *= sc;
    }

#pragma unroll
    for (int ks = 0; ks < 2; ++ks) {
      int kb = ks * 64 + kgrp * 16;
      bf16x8 ap = *(const bf16x8*)((const char*)sPw + ((lrow * 128 + kb) ^ ((lrow & 7) << 4)));
#pragma unroll
      for (int nf = 0; nf < 4; ++nf) {
        int vr = nf * 16 + lrow;
        bf16x8 bv = *(const bf16x8*)((const char*)sV + vr * 128 + (kb ^ ((vr & 7) << 4)));
        O[nf] = MFMA16(ap, bv, O[nf]);
      }
    }
    __syncthreads();
  }

#pragma unroll
  for (int r = 0; r < 4; ++r) {
    float inv = 1.0f / l_run[r];
    int trow = b * 512 + q0 + wave * 16 + kgrp * 4 + r;
#pragma unroll
    for (int nf = 0; nf < 4; ++nf) {
      int col = h * 64 + nf * 16 + lrow;
      float v = O[nf][r] * inv;
      u16 hb = f2b(v);
      ctx_hi[(size_t)trow * 1024 + col] = hb;
      ctx_lo[(size_t)trow * 1024 + col] = f2b(v - b2f(hb));
    }
  }
}

// ---------------- launch ----------------
extern "C" void kernel_launch(void* const* d_in, const int* in_sizes, int n_in,
                              void* d_out, int out_size, void* d_ws, size_t ws_size,
                              hipStream_t stream) {
  const float* x     = (const float*)d_in[0];
  const int*   mask  = (const int*)d_in[1];
  const float* w_dkv = (const float*)d_in[2];
  const float* b_dkv = (const float*)d_in[3];
  const float* w_dq  = (const float*)d_in[4];
  const float* b_dq  = (const float*)d_in[5];
  const float* w_uq  = (const float*)d_in[6];
  const float* b_uq  = (const float*)d_in[7];
  const float* w_uk  = (const float*)d_in[8];
  const float* b_uk  = (const float*)d_in[9];
  const float* w_uv  = (const float*)d_in[10];
  const float* b_uv  = (const float*)d_in[11];
  const float* w_qr  = (const float*)d_in[12];
  const float* b_qr  = (const float*)d_in[13];
  const float* w_kr  = (const float*)d_in[14];
  const float* b_kr  = (const float*)d_in[15];
  const float* w_fc  = (const float*)d_in[16];
  const float* b_fc  = (const float*)d_in[17];
  float* out = (float*)d_out;

  char* ws = (char*)d_ws;
  size_t off = 0;
  auto alloc = [&](size_t bytes) -> void* {
    void* p = ws + off;
    off += (bytes + 255) & ~(size_t)255;
    return p;
  };
  u16* xhi   = (u16*)alloc(33554432);   // 8192x2048 bf16 (later reused as qr_f32)
  u16* xlo   = (u16*)alloc(33554432);   // (later reused as v_f32)
  u16* WfTh  = (u16*)alloc(4194304);    // [1024][2048]
  u16* WfTl  = (u16*)alloc(4194304);
  u16* WuqTh = (u16*)alloc(1048576);    // [1024][512]
  u16* WuqTl = (u16*)alloc(1048576);
  u16* WqrTh = (u16*)alloc(1048576);
  u16* WqrTl = (u16*)alloc(1048576);
  u16* WukTh = (u16*)alloc(1048576);
  u16* WukTl = (u16*)alloc(1048576);
  u16* WuvTh = (u16*)alloc(1048576);
  u16* WuvTl = (u16*)alloc(1048576);
  u16* WkrTh = (u16*)alloc(65536);      // [64][512]
  u16* WkrTl = (u16*)alloc(65536);
  u16* WfcTh = (u16*)alloc(4194304);    // [2048][1024]
  u16* WfcTl = (u16*)alloc(4194304);
  u16* chi   = (u16*)alloc(16777216);   // c = [ckv|cq] [8192][1024] bf16 (reused as ctx_hi)
  u16* clo   = (u16*)alloc(16777216);   // (reused as ctx_lo)
  u16* Qb    = (u16*)alloc(33554432);   // [256][512][128]
  u16* Kb    = (u16*)alloc(33554432);
  u16* Vt    = (u16*)alloc(16777216);   // [256][64][512]
  float* krf = (float*)alloc(2097152);  // [8192][64]
  float* qrf = (float*)xhi;             // [8192][1024] (aliases dead xhi)
  float* vf  = (float*)xlo;             // [8192][1024] (aliases dead xlo)
  u16* ctxh = chi;                      // attention output aliases dead c
  u16* ctxl = clo;
  (void)ws_size; (void)in_sizes; (void)n_in; (void)out_size;

  const float scale = 1.0f / (sqrtf(128.0f) + sqrtf(64.0f));
  const float scale2 = scale * 1.4426950408889634f;  // log2(e) folded

  split_x_kernel<<<16384, 256, 0, stream>>>(x, xhi, xlo, 4194304);
  wtrans_kernel<<<dim3(64, 16), 256, 0, stream>>>(w_dkv, 512, WfTh, WfTl, 0, 2048);
  wtrans_kernel<<<dim3(64, 16), 256, 0, stream>>>(w_dq, 512, WfTh, WfTl, 512, 2048);
  wtrans_kernel<<<dim3(16, 32), 256, 0, stream>>>(w_uq, 1024, WuqTh, WuqTl, 0, 512);
  wtrans_kernel<<<dim3(16, 32), 256, 0, stream>>>(w_qr, 1024, WqrTh, WqrTl, 0, 512);
  wtrans_kernel<<<dim3(16, 32), 256, 0, stream>>>(w_uk, 1024, WukTh, WukTl, 0, 512);
  wtrans_kernel<<<dim3(16, 32), 256, 0, stream>>>(w_uv, 1024, WuvTh, WuvTl, 0, 512);
  wtrans_kernel<<<dim3(16, 2), 256, 0, stream>>>(w_kr, 64, WkrTh, WkrTl, 0, 512);
  wtrans_kernel<<<dim3(32, 64), 256, 0, stream>>>(w_fc, 2048, WfcTh, WfcTl, 0, 1024);

  // c = x @ [w_dkv | w_dq] + [b_dkv | b_dq]   -> bf16 [8192][1024], 3-term
  gemm3_kernel<3, 3><<<dim3(64, 8), 256, 0, stream>>>(
      xhi, xlo, 2048, WfTh, WfTl, 2048, b_dkv, b_dq, 512,
      (void*)chi, nullptr, 1024, 2048, 1024);
  // q_c = c_q @ w_uq -> Qb head layout (2-term: c already bf16-rounded)
  gemm3_kernel<2, 2><<<dim3(64, 8), 256, 0, stream>>>(
      chi + 512, nullptr, 1024, WuqTh, WuqTl, 512, b_uq, b_uq, 1024,
      (void*)Qb, nullptr, 1024, 512, 0);
  // q_r pre-rope -> f32 (2-term)
  gemm3_kernel<0, 2><<<dim3(64, 8), 256, 0, stream>>>(
      chi + 512, nullptr, 1024, WqrTh, WqrTl, 512, b_qr, b_qr, 1024,
      (void*)qrf, nullptr, 1024, 512, 1024);
  // k_c = c_kv @ w_uk -> Kb head layout (2-term)
  gemm3_kernel<2, 2><<<dim3(64, 8), 256, 0, stream>>>(
      chi, nullptr, 1024, WukTh, WukTl, 512, b_uk, b_uk, 1024,
      (void*)Kb, nullptr, 1024, 512, 0);
  // v = c_kv @ w_uv -> f32 (2-term)
  gemm3_kernel<0, 2><<<dim3(64, 8), 256, 0, stream>>>(
      chi, nullptr, 1024, WuvTh, WuvTl, 512, b_uv, b_uv, 1024,
      (void*)vf, nullptr, 1024, 512, 1024);
  // k_r pre-rope -> f32 (N=64, 2-term)
  gemm3_kernel<0, 2><<<dim3(64, 1), 256, 0, stream>>>(
      chi, nullptr, 1024, WkrTh, WkrTl, 512, b_kr, b_kr, 64,
      (void*)krf, nullptr, 64, 512, 64);

  ropeq_kernel<<<16384, 256, 0, stream>>>(qrf, Qb);
  ropek_kernel<<<1024, 256, 0, stream>>>(krf, Kb);
  vtrans_kernel<<<dim3(256, 8), 256, 0, stream>>>(vf, Vt);

  attn_kernel<<<dim3(256, 8), 256, 0, stream>>>(Qb, Kb, Vt, mask, ctxh, ctxl, scale2);

  // out = ctx @ w_fc + b_fc  -> f32 [8192][2048], 3-term
  gemm3_kernel<0, 3><<<dim3(64, 16), 256, 0, stream>>>(
      ctxh, ctxl, 1024, WfcTh, WfcTl, 1024, b_fc, b_fc, 2048,
      (void*)out, nullptr, 2048, 1024, 2048);
}

// Round 3
// 500.674 us; speedup vs baseline: 1.1830x; 1.1259x over previous
//
#include <hip/hip_runtime.h>
#include <cstdint>
#include <cmath>

typedef unsigned short u16;
typedef unsigned int   u32;
typedef _Float16 f16x8 __attribute__((ext_vector_type(8)));
typedef float f32x4  __attribute__((ext_vector_type(4)));

#define MFMAH(a, b, c) __builtin_amdgcn_mfma_f32_16x16x32_f16((a), (b), (c), 0, 0, 0)

__device__ __forceinline__ u16 f2h(float f) {
  _Float16 h = (_Float16)f;
  return __builtin_bit_cast(u16, h);
}
__device__ __forceinline__ float h2f(u16 u) {
  return (float)__builtin_bit_cast(_Float16, u);
}
__device__ __forceinline__ float fexp2(float x) { return __builtin_amdgcn_exp2f(x); }
__device__ __forceinline__ void async16(const void* g, void* l) {
  __builtin_amdgcn_global_load_lds((const __attribute__((address_space(1))) u32*)g,
                                   (__attribute__((address_space(3))) u32*)l, 16, 0, 0);
}

// ---------------- prep: convert x to f16 ----------------
__global__ void convert_x_kernel(const float* __restrict__ x, u16* __restrict__ xh, int n4) {
  int i = blockIdx.x * blockDim.x + threadIdx.x;
  if (i >= n4) return;
  float4 v = reinterpret_cast<const float4*>(x)[i];
  uint2 p;
  p.x = (u32)f2h(v.x) | ((u32)f2h(v.y) << 16);
  p.y = (u32)f2h(v.z) | ((u32)f2h(v.w) << 16);
  reinterpret_cast<uint2*>(xh)[i] = p;
}

// ---------------- prep: transpose weight [K,N] f32 -> [N][K] f16 (hi[/lo]) ----------------
template <int NOUT>
__global__ void wtrans_kernel(const float* __restrict__ W, int N,
                              u16* __restrict__ Thi, u16* __restrict__ Tlo,
                              int row_off, int dst_ld) {
  __shared__ float tile[32][33];
  int k0 = blockIdx.x * 32, n0 = blockIdx.y * 32;
  int tx = threadIdx.x & 31, ty = threadIdx.x >> 5;  // 32 x 8
#pragma unroll
  for (int i = 0; i < 32; i += 8)
    tile[ty + i][tx] = W[(size_t)(k0 + ty + i) * N + n0 + tx];
  __syncthreads();
#pragma unroll
  for (int i = 0; i < 32; i += 8) {
    float v = tile[tx][ty + i];
    size_t o = (size_t)(row_off + n0 + ty + i) * dst_ld + k0 + tx;
    u16 h = f2h(v);
    Thi[o] = h;
    if constexpr (NOUT == 2) Tlo[o] = f2h(v - h2f(h));
  }
}

// ---------------- generic f16 GEMM ----------------
// C[M,N] = A[M,K] @ B^T-stored-[N,K] + bias
// TERMS==2: B split hi/lo (a*bh + a*bl).  TERMS==1: B single.
// MODE 0: f32 out. MODE 2: f16 to [b,h,s,128] head layout. MODE 3: f16 out.
template <int MODE, int TERMS>
__global__ __launch_bounds__(256, TERMS == 2 ? 3 : 4) void gemmh_kernel(
    const u16* __restrict__ Ah, int lda,
    const u16* __restrict__ Bhi, const u16* __restrict__ Blo, int ldb,
    const float* __restrict__ bias, const float* __restrict__ bias2, int bsplit,
    void* __restrict__ out0, int N, int K, int ldc) {
  __shared__ u16 lA[128 * 64];
  __shared__ u16 lB[TERMS][128 * 64];
  const int tid = threadIdx.x;
  const int wave = tid >> 6, lane = tid & 63;
  const int lrow = lane & 15, kgrp = lane >> 4;
  // bijective XCD-aware swizzle (all grids are multiples of 8)
  const int nwg = gridDim.x * gridDim.y;
  const int orig = blockIdx.y * gridDim.x + blockIdx.x;
  const int swz = (orig & 7) * (nwg >> 3) + (orig >> 3);
  const int bm = (swz % gridDim.x) * 128, bn = (swz / gridDim.x) * 128;
  const int wm = (wave >> 1) * 64, wn = (wave & 1) * 64;
  const int srow = lane >> 3, sg = lane & 7;

  f32x4 acc[4][4];
  const f32x4 zero = {0.f, 0.f, 0.f, 0.f};
#pragma unroll
  for (int i = 0; i < 4; ++i)
#pragma unroll
    for (int j = 0; j < 4; ++j) acc[i][j] = zero;

  for (int kt = 0; kt < K; kt += 64) {
#pragma unroll
    for (int ii = 0; ii < 4; ++ii) {
      int inst = wave * 4 + ii;
      int row = inst * 8 + srow;                 // 0..127
      int koff = kt + ((sg ^ (row & 7)) << 3);   // pre-swizzled source granule
      async16(Ah + (size_t)(bm + row) * lda + koff, &lA[inst * 512]);
      int brow = bn + row;
      if (brow > N - 1) brow = N - 1;
      async16(Bhi + (size_t)brow * ldb + koff, &lB[0][inst * 512]);
      if constexpr (TERMS == 2)
        async16(Blo + (size_t)brow * ldb + koff, &lB[TERMS - 1][inst * 512]);
    }
    asm volatile("s_waitcnt vmcnt(0)" ::: "memory");
    __syncthreads();

#pragma unroll
    for (int ks = 0; ks < 2; ++ks) {
      f16x8 ah[4], b0v[4], b1v[4];
#pragma unroll
      for (int mi = 0; mi < 4; ++mi) {
        int row = wm + mi * 16 + lrow;
        int off = row * 128 + ((ks * 64 + kgrp * 16) ^ ((row & 7) << 4));
        ah[mi] = *(const f16x8*)((const char*)lA + off);
      }
#pragma unroll
      for (int ni = 0; ni < 4; ++ni) {
        int row = wn + ni * 16 + lrow;
        int off = row * 128 + ((ks * 64 + kgrp * 16) ^ ((row & 7) << 4));
        b0v[ni] = *(const f16x8*)((const char*)lB[0] + off);
        if constexpr (TERMS == 2)
          b1v[ni] = *(const f16x8*)((const char*)lB[TERMS - 1] + off);
      }
#pragma unroll
      for (int mi = 0; mi < 4; ++mi)
#pragma unroll
        for (int ni = 0; ni < 4; ++ni) {
          acc[mi][ni] = MFMAH(ah[mi], b0v[ni], acc[mi][ni]);
          if constexpr (TERMS == 2)
            acc[mi][ni] = MFMAH(ah[mi], b1v[ni], acc[mi][ni]);
        }
    }
    __syncthreads();
  }

#pragma unroll
  for (int mi = 0; mi < 4; ++mi) {
#pragma unroll
    for (int ni = 0; ni < 4; ++ni) {
      int col = bn + wn + ni * 16 + lrow;
      if (col >= N) continue;
      float bv = (col < bsplit) ? bias[col] : bias2[col - bsplit];
      int row0 = bm + wm + mi * 16 + kgrp * 4;
#pragma unroll
      for (int r = 0; r < 4; ++r) {
        int row = row0 + r;
        float v = acc[mi][ni][r] + bv;
        if (MODE == 0) {
          ((float*)out0)[(size_t)row * ldc + col] = v;
        } else if (MODE == 3) {
          ((u16*)out0)[(size_t)row * ldc + col] = f2h(v);
        } else {
          int bb = row >> 9, ss = row & 511, hh = col >> 6, dd = col & 63;
          ((u16*)out0)[(((size_t)(bb * 16 + hh) * 512 + ss) << 7) + dd] = f2h(v);
        }
      }
    }
  }
}

// ---------------- rope on q_r -> Qb[...,64:128] (f16) ----------------
__global__ void ropeq_kernel(const float* __restrict__ qr, u16* __restrict__ Qb) {
  int idx = blockIdx.x * 256 + threadIdx.x;  // 8192*512
  int t = idx >> 9;
  int rem = idx & 511;
  int h = rem >> 5, i = rem & 31;
  float2 v = reinterpret_cast<const float2*>(qr + (size_t)t * 1024 + h * 64)[i];
  float theta = exp2f((float)i * (-13.287712379549449f / 32.0f));  // 10000^(-i/32)
  float ang = (float)(t & 511) * theta;
  float sn = sinf(ang), cs = cosf(ang);
  // reference has swapped names: cos_pos=sin(.), sin_pos=cos(.)
  float o0 = v.x * sn - v.y * cs;
  float o1 = v.y * sn + v.x * cs;
  size_t o = ((size_t)((t >> 9) * 16 + h) * 512 + (t & 511)) * 128 + 64 + 2 * i;
  u32 pk = (u32)f2h(o0) | ((u32)f2h(o1) << 16);
  *reinterpret_cast<u32*>(Qb + o) = pk;
}

// ---------------- rope on k_r -> broadcast into Kb[...,64:128] (f16) ----------------
__global__ void ropek_kernel(const float* __restrict__ kr, u16* __restrict__ Kb) {
  int idx = blockIdx.x * 256 + threadIdx.x;  // 8192*32
  int t = idx >> 5, i = idx & 31;
  float2 v = reinterpret_cast<const float2*>(kr + (size_t)t * 64)[i];
  float theta = exp2f((float)i * (-13.287712379549449f / 32.0f));
  float ang = (float)(t & 511) * theta;
  float sn = sinf(ang), cs = cosf(ang);
  float o0 = v.x * sn - v.y * cs;
  float o1 = v.y * sn + v.x * cs;
  u32 pk = (u32)f2h(o0) | ((u32)f2h(o1) << 16);
  int bb = t >> 9, ss = t & 511;
  size_t base = (size_t)bb * 16 * 512 * 128;
#pragma unroll
  for (int hh = 0; hh < 16; ++hh)
    *reinterpret_cast<u32*>(Kb + base + ((size_t)(hh * 512 + ss)) * 128 + 64 + 2 * i) = pk;
}

// ---------------- transpose v [8192,1024]f32 -> Vt [bh][64][512] f16 ----------------
__global__ void vtrans_kernel(const float* __restrict__ v, u16* __restrict__ Vt) {
  __shared__ u16 tl[64][65];
  const int bh = blockIdx.x, b = bh >> 4, h = bh & 15;
  const int s0 = blockIdx.y * 64;
  const int tid = threadIdx.x;
  const int d = tid & 63, si = tid >> 6;
#pragma unroll
  for (int i = 0; i < 64; i += 4)
    tl[si + i][d] = f2h(v[((size_t)(b * 512 + s0 + si + i)) * 1024 + h * 64 + d]);
  __syncthreads();
  const int sj = tid & 63, dd = tid >> 6;
#pragma unroll
  for (int i = 0; i < 64; i += 4)
    Vt[((size_t)bh * 64 + dd + i) * 512 + s0 + sj] = tl[sj][dd + i];
}

// ---------------- fused flash attention per (b,h, 64-row q tile) ----------------
// logits kept in log2 domain: s' = S*scale*log2e + maskbias
__global__ __launch_bounds__(256, 3) void attn_kernel(
    const u16* __restrict__ Qb, const u16* __restrict__ Kb, const u16* __restrict__ Vt,
    const int* __restrict__ mask, u16* __restrict__ ctx,
    float scale2) {
  __shared__ u16 sQ[64 * 128];
  __shared__ u16 sK[64 * 128];
  __shared__ u16 sV[64 * 64];
  __shared__ u16 sP[4][16 * 64];
  const int tid = threadIdx.x, wave = tid >> 6, lane = tid & 63;
  const int lrow = lane & 15, kgrp = lane >> 4;
  const int bh = blockIdx.x, b = bh >> 4, h = bh & 15;
  const int q0 = blockIdx.y * 64;
  const size_t qkbase = (size_t)bh * 512 * 128;
  const size_t vbase = (size_t)bh * 64 * 512;
  u16* __restrict__ sPw = sP[wave];

  // loop-invariant P-store offsets (u16-element units)
  u32 poff[4][4];
#pragma unroll
  for (int r = 0; r < 4; ++r) {
    int qp = kgrp * 4 + r;
    int xr = (qp & 7) << 3;
#pragma unroll
    for (int nf = 0; nf < 4; ++nf) poff[r][nf] = (u32)((qp * 64 + nf * 16 + lrow) ^ xr);
  }

  {  // stage Q tile once (rows 256B = 16 granules, xor-swizzled source)
    int g = lane & 15, rr = lane >> 4;
#pragma unroll
    for (int ii = 0; ii < 4; ++ii) {
      int inst = wave * 4 + ii;
      int row = inst * 4 + rr;
      int perm = (g & 8) | ((g & 7) ^ (row & 7));
      async16(Qb + qkbase + (size_t)(q0 + row) * 128 + perm * 8, &sQ[inst * 512]);
    }
  }

  const f32x4 zero = {0.f, 0.f, 0.f, 0.f};
  f32x4 O[4];
#pragma unroll
  for (int nf = 0; nf < 4; ++nf) O[nf] = zero;
  float m_run[4], l_run[4];
#pragma unroll
  for (int r = 0; r < 4; ++r) { m_run[r] = -1e30f; l_run[r] = 0.f; }

  for (int kvt = 0; kvt < 8; ++kvt) {
    const int kv0 = kvt * 64;
    {
      int g = lane & 15, rr = lane >> 4;
#pragma unroll
      for (int ii = 0; ii < 4; ++ii) {
        int inst = wave * 4 + ii;
        int row = inst * 4 + rr;
        int perm = (g & 8) | ((g & 7) ^ (row & 7));
        async16(Kb + qkbase + (size_t)(kv0 + row) * 128 + perm * 8, &sK[inst * 512]);
      }
      int g2 = lane & 7, r2 = lane >> 3;
#pragma unroll
      for (int ii = 0; ii < 2; ++ii) {
        int inst = wave * 2 + ii;
        int row = inst * 8 + r2;
        async16(Vt + vbase + (size_t)row * 512 + kv0 + ((g2 ^ (row & 7)) << 3),
                &sV[inst * 512]);
      }
    }
    // mask -> additive bias while loads are in flight
    float mb[4];
#pragma unroll
    for (int nf = 0; nf < 4; ++nf)
      mb[nf] = (mask[b * 512 + kv0 + nf * 16 + lrow] != 0) ? 0.f : -1e30f;

    asm volatile("s_waitcnt vmcnt(0)" ::: "memory");
    __syncthreads();

    f32x4 S[4];
#pragma unroll
    for (int nf = 0; nf < 4; ++nf) S[nf] = zero;
#pragma unroll
    for (int ks = 0; ks < 4; ++ks) {
      int qrow = wave * 16 + lrow;
      int kb = ks * 64 + kgrp * 16;
      f16x8 aq = *(const f16x8*)((const char*)sQ + qrow * 256 + (kb ^ ((qrow & 7) << 4)));
#pragma unroll
      for (int nf = 0; nf < 4; ++nf) {
        int krow = nf * 16 + lrow;
        f16x8 bk = *(const f16x8*)((const char*)sK + krow * 256 + (kb ^ ((krow & 7) << 4)));
        S[nf] = MFMAH(aq, bk, S[nf]);
      }
    }

    float pvv[4][4];
    float tmax[4] = {-1e30f, -1e30f, -1e30f, -1e30f};
#pragma unroll
    for (int nf = 0; nf < 4; ++nf) {
#pragma unroll
      for (int r = 0; r < 4; ++r) {
        float v = fmaf(S[nf][r], scale2, mb[nf]);
        pvv[nf][r] = v;
        tmax[r] = fmaxf(tmax[r], v);
      }
    }
#pragma unroll
    for (int r = 0; r < 4; ++r) {
#pragma unroll
      for (int mv = 1; mv < 16; mv <<= 1)
        tmax[r] = fmaxf(tmax[r], __shfl_xor(tmax[r], mv, 64));
    }
#pragma unroll
    for (int r = 0; r < 4; ++r) {
      float newm = fmaxf(m_run[r], tmax[r]);
      float sc = fexp2(m_run[r] - newm);
      m_run[r] = newm;
      float ts = 0.f;
#pragma unroll
      for (int nf = 0; nf < 4; ++nf) {
        float pe = fexp2(pvv[nf][r] - newm);
        sPw[poff[r][nf]] = f2h(pe);
        ts += pe;
      }
#pragma unroll
      for (int mv = 1; mv < 16; mv <<= 1) ts += __shfl_xor(ts, mv, 64);
      l_run[r] = l_run[r] * sc + ts;
#pragma unroll
      for (int nf = 0; nf < 4; ++nf) O[nf][r] *= sc;
    }

#pragma unroll
    for (int ks = 0; ks < 2; ++ks) {
      int kb = ks * 64 + kgrp * 16;
      f16x8 ap = *(const f16x8*)((const char*)sPw + ((lrow * 128 + kb) ^ ((lrow & 7) << 4)));
#pragma unroll
      for (int nf = 0; nf < 4; ++nf) {
        int vr = nf * 16 + lrow;
        f16x8 bv = *(const f16x8*)((const char*)sV + vr * 128 + (kb ^ ((vr & 7) << 4)));
        O[nf] = MFMAH(ap, bv, O[nf]);
      }
    }
    __syncthreads();
  }

#pragma unroll
  for (int r = 0; r < 4; ++r) {
    float inv = 1.0f / l_run[r];
    int trow = b * 512 + q0 + wave * 16 + kgrp * 4 + r;
#pragma unroll
    for (int nf = 0; nf < 4; ++nf) {
      int col = h * 64 + nf * 16 + lrow;
      ctx[(size_t)trow * 1024 + col] = f2h(O[nf][r] * inv);
    }
  }
}

// ---------------- launch ----------------
extern "C" void kernel_launch(void* const* d_in, const int* in_sizes, int n_in,
                              void* d_out, int out_size, void* d_ws, size_t ws_size,
                              hipStream_t stream) {
  const float* x     = (const float*)d_in[0];
  const int*   mask  = (const int*)d_in[1];
  const float* w_dkv = (const float*)d_in[2];
  const float* b_dkv = (const float*)d_in[3];
  const float* w_dq  = (const float*)d_in[4];
  const float* b_dq  = (const float*)d_in[5];
  const float* w_uq  = (const float*)d_in[6];
  const float* b_uq  = (const float*)d_in[7];
  const float* w_uk  = (const float*)d_in[8];
  const float* b_uk  = (const float*)d_in[9];
  const float* w_uv  = (const float*)d_in[10];
  const float* b_uv  = (const float*)d_in[11];
  const float* w_qr  = (const float*)d_in[12];
  const float* b_qr  = (const float*)d_in[13];
  const float* w_kr  = (const float*)d_in[14];
  const float* b_kr  = (const float*)d_in[15];
  const float* w_fc  = (const float*)d_in[16];
  const float* b_fc  = (const float*)d_in[17];
  float* out = (float*)d_out;

  char* ws = (char*)d_ws;
  size_t off = 0;
  auto alloc = [&](size_t bytes) -> void* {
    void* p = ws + off;
    off += (bytes + 255) & ~(size_t)255;
    return p;
  };
  u16* xh    = (u16*)alloc(33554432);   // 8192x2048 f16 (later reused as qr_f32)
  u16* WfTh  = (u16*)alloc(4194304);    // [1024][2048] f16
  u16* WfTl  = (u16*)alloc(4194304);
  u16* WuqT  = (u16*)alloc(1048576);    // [1024][512] f16 single
  u16* WqrT  = (u16*)alloc(1048576);
  u16* WukT  = (u16*)alloc(1048576);
  u16* WuvT  = (u16*)alloc(1048576);
  u16* WkrT  = (u16*)alloc(65536);      // [64][512]
  u16* WfcTh = (u16*)alloc(4194304);    // [2048][1024]
  u16* WfcTl = (u16*)alloc(4194304);
  u16* c     = (u16*)alloc(16777216);   // c = [ckv|cq] [8192][1024] f16 (reused as ctx)
  u16* Qb    = (u16*)alloc(33554432);   // [256][512][128] f16
  u16* Kb    = (u16*)alloc(33554432);
  u16* Vt    = (u16*)alloc(16777216);   // [256][64][512] f16
  float* krf = (float*)alloc(2097152);  // [8192][64] f32
  float* vf  = (float*)alloc(33554432); // [8192][1024] f32
  float* qrf = (float*)xh;              // [8192][1024] f32 (aliases dead xh)
  u16* ctx  = c;                        // attention output aliases dead c
  (void)ws_size; (void)in_sizes; (void)n_in; (void)out_size;

  const float scale = 1.0f / (sqrtf(128.0f) + sqrtf(64.0f));
  const float scale2 = scale * 1.4426950408889634f;  // log2(e) folded

  convert_x_kernel<<<16384, 256, 0, stream>>>(x, xh, 4194304);
  wtrans_kernel<2><<<dim3(64, 16), 256, 0, stream>>>(w_dkv, 512, WfTh, WfTl, 0, 2048);
  wtrans_kernel<2><<<dim3(64, 16), 256, 0, stream>>>(w_dq, 512, WfTh, WfTl, 512, 2048);
  wtrans_kernel<1><<<dim3(16, 32), 256, 0, stream>>>(w_uq, 1024, WuqT, nullptr, 0, 512);
  wtrans_kernel<1><<<dim3(16, 32), 256, 0, stream>>>(w_qr, 1024, WqrT, nullptr, 0, 512);
  wtrans_kernel<1><<<dim3(16, 32), 256, 0, stream>>>(w_uk, 1024, WukT, nullptr, 0, 512);
  wtrans_kernel<1><<<dim3(16, 32), 256, 0, stream>>>(w_uv, 1024, WuvT, nullptr, 0, 512);
  wtrans_kernel<1><<<dim3(16, 2), 256, 0, stream>>>(w_kr, 64, WkrT, nullptr, 0, 512);
  wtrans_kernel<2><<<dim3(32, 64), 256, 0, stream>>>(w_fc, 2048, WfcTh, WfcTl, 0, 1024);

  // c = x @ [w_dkv | w_dq] + [b_dkv | b_dq]   -> f16 [8192][1024], 2-term
  gemmh_kernel<3, 2><<<dim3(64, 8), 256, 0, stream>>>(
      xh, 2048, WfTh, WfTl, 2048, b_dkv, b_dq, 512,
      (void*)c, 1024, 2048, 1024);
  // q_c = c_q @ w_uq -> Qb head layout (1-term)
  gemmh_kernel<2, 1><<<dim3(64, 8), 256, 0, stream>>>(
      c + 512, 1024, WuqT, nullptr, 512, b_uq, b_uq, 1024,
      (void*)Qb, 1024, 512, 0);
  // q_r pre-rope -> f32 (1-term)
  gemmh_kernel<0, 1><<<dim3(64, 8), 256, 0, stream>>>(
      c + 512, 1024, WqrT, nullptr, 512, b_qr, b_qr, 1024,
      (void*)qrf, 1024, 512, 1024);
  // k_c = c_kv @ w_uk -> Kb head layout (1-term)
  gemmh_kernel<2, 1><<<dim3(64, 8), 256, 0, stream>>>(
      c, 1024, WukT, nullptr, 512, b_uk, b_uk, 1024,
      (void*)Kb, 1024, 512, 0);
  // v = c_kv @ w_uv -> f32 (1-term)
  gemmh_kernel<0, 1><<<dim3(64, 8), 256, 0, stream>>>(
      c, 1024, WuvT, nullptr, 512, b_uv, b_uv, 1024,
      (void*)vf, 1024, 512, 1024);
  // k_r pre-rope -> f32 (N=64, 1-term)
  gemmh_kernel<0, 1><<<dim3(64, 1), 256, 0, stream>>>(
      c, 1024, WkrT, nullptr, 512, b_kr, b_kr, 64,
      (void*)krf, 64, 512, 64);

  ropeq_kernel<<<16384, 256, 0, stream>>>(qrf, Qb);
  ropek_kernel<<<1024, 256, 0, stream>>>(krf, Kb);
  vtrans_kernel<<<dim3(256, 8), 256, 0, stream>>>(vf, Vt);

  attn_kernel<<<dim3(256, 8), 256, 0, stream>>>(Qb, Kb, Vt, mask, ctx, scale2);

  // out = ctx @ w_fc + b_fc  -> f32 [8192][2048], 2-term
  gemmh_kernel<0, 2><<<dim3(64, 16), 256, 0, stream>>>(
      ctx, 1024, WfcTh, WfcTl, 1024, b_fc, b_fc, 2048,
      (void*)out, 2048, 1024, 2048);
}

// Round 4
// 458.744 us; speedup vs baseline: 1.2912x; 1.0914x over previous
//
#include <hip/hip_runtime.h>
#include <cstdint>
#include <cmath>

typedef unsigned short u16;
typedef unsigned int   u32;
typedef _Float16 f16x8 __attribute__((ext_vector_type(8)));
typedef float f32x4  __attribute__((ext_vector_type(4)));

#define MFMAH(a, b, c) __builtin_amdgcn_mfma_f32_16x16x32_f16((a), (b), (c), 0, 0, 0)

__device__ __forceinline__ u16 f2h(float f) {
  _Float16 h = (_Float16)f;
  return __builtin_bit_cast(u16, h);
}
__device__ __forceinline__ float h2f(u16 u) {
  return (float)__builtin_bit_cast(_Float16, u);
}
__device__ __forceinline__ float fexp2(float x) { return __builtin_amdgcn_exp2f(x); }
__device__ __forceinline__ void async16(const void* g, void* l) {
  __builtin_amdgcn_global_load_lds((const __attribute__((address_space(1))) u32*)g,
                                   (__attribute__((address_space(3))) u32*)l, 16, 0, 0);
}

// ---------------- prep: sin/cos table [512 pos][32 freq] ----------------
__global__ void stab_kernel(float2* __restrict__ stab) {
  int idx = blockIdx.x * 256 + threadIdx.x;  // 16384
  int s = idx >> 5, i = idx & 31;
  float theta = exp2f((float)i * (-13.287712379549449f / 32.0f));  // 10000^(-i/32)
  float ang = (float)s * theta;
  stab[idx] = make_float2(sinf(ang), cosf(ang));
}

// ---------------- prep: concatenated bias vectors ----------------
__global__ void biascat_kernel(const float* __restrict__ buq, const float* __restrict__ bqr,
                               const float* __restrict__ buk, const float* __restrict__ buv,
                               const float* __restrict__ bkr,
                               float* __restrict__ biasQ, float* __restrict__ biasKV) {
  int idx = blockIdx.x * 256 + threadIdx.x;
  if (idx < 2048) biasQ[idx] = (idx < 1024) ? buq[idx] : bqr[idx - 1024];
  int j = idx - 2048;
  if (j >= 0 && j < 2176)
    biasKV[j] = (j < 1024) ? buk[j]
              : (j < 2048) ? buv[j - 1024]
              : (j < 2112) ? bkr[j - 2048] : 0.f;
}

// ---------------- prep: convert x to f16 ----------------
__global__ void convert_x_kernel(const float* __restrict__ x, u16* __restrict__ xh, int n4) {
  int i = blockIdx.x * blockDim.x + threadIdx.x;
  if (i >= n4) return;
  float4 v = reinterpret_cast<const float4*>(x)[i];
  uint2 p;
  p.x = (u32)f2h(v.x) | ((u32)f2h(v.y) << 16);
  p.y = (u32)f2h(v.z) | ((u32)f2h(v.w) << 16);
  reinterpret_cast<uint2*>(xh)[i] = p;
}

// ---------------- prep: transpose weight [K,N] f32 -> [N][K] f16 (hi[/lo]) ----------------
template <int NOUT>
__global__ void wtrans_kernel(const float* __restrict__ W, int N,
                              u16* __restrict__ Thi, u16* __restrict__ Tlo,
                              int row_off, int dst_ld) {
  __shared__ float tile[32][33];
  int k0 = blockIdx.x * 32, n0 = blockIdx.y * 32;
  int tx = threadIdx.x & 31, ty = threadIdx.x >> 5;  // 32 x 8
#pragma unroll
  for (int i = 0; i < 32; i += 8)
    tile[ty + i][tx] = W[(size_t)(k0 + ty + i) * N + n0 + tx];
  __syncthreads();
#pragma unroll
  for (int i = 0; i < 32; i += 8) {
    float v = tile[tx][ty + i];
    size_t o = (size_t)(row_off + n0 + ty + i) * dst_ld + k0 + tx;
    u16 h = f2h(v);
    Thi[o] = h;
    if constexpr (NOUT == 2) Tlo[o] = f2h(v - h2f(h));
  }
}

// ---------------- generic f16 GEMM ----------------
// C[M,N] = A[M,K] @ B^T-stored-[N,K] + bias
// TERMS==2: B split hi/lo (a*bh + a*bl).  TERMS==1: B single.
// MODE 0: f32 out (ldc).
// MODE 3: f16 out (ldc).
// MODE 7: q-side fused: col<1024 -> Qb content slots [b,h,s,0:64];
//         col>=1024 -> rope applied (shfl pair + table), Qb slots [64:128].
// MODE 6: kv-side fused: col<1024 -> Kb content slots; col<2048 -> Vt [bh][d][s];
//         col>=2048 -> f32 krf (ld 128).
template <int MODE, int TERMS>
__global__ __launch_bounds__(256, TERMS == 2 ? 3 : 4) void gemmh_kernel(
    const u16* __restrict__ Ah, int lda,
    const u16* __restrict__ Bhi, const u16* __restrict__ Blo, int ldb,
    const float* __restrict__ bias, const float* __restrict__ bias2, int bsplit,
    void* __restrict__ out0, void* __restrict__ out1, void* __restrict__ out2,
    const float2* __restrict__ stab, int N, int K, int ldc) {
  __shared__ u16 lA[128 * 64];
  __shared__ u16 lB[TERMS][128 * 64];
  const int tid = threadIdx.x;
  const int wave = tid >> 6, lane = tid & 63;
  const int lrow = lane & 15, kgrp = lane >> 4;
  // bijective XCD-aware swizzle (all grids are multiples of 8)
  const int nwg = gridDim.x * gridDim.y;
  const int orig = blockIdx.y * gridDim.x + blockIdx.x;
  const int swz = (orig & 7) * (nwg >> 3) + (orig >> 3);
  const int bm = (swz % gridDim.x) * 128, bn = (swz / gridDim.x) * 128;
  const int wm = (wave >> 1) * 64, wn = (wave & 1) * 64;
  const int srow = lane >> 3, sg = lane & 7;

  f32x4 acc[4][4];
  const f32x4 zero = {0.f, 0.f, 0.f, 0.f};
#pragma unroll
  for (int i = 0; i < 4; ++i)
#pragma unroll
    for (int j = 0; j < 4; ++j) acc[i][j] = zero;

  for (int kt = 0; kt < K; kt += 64) {
#pragma unroll
    for (int ii = 0; ii < 4; ++ii) {
      int inst = wave * 4 + ii;
      int row = inst * 8 + srow;                 // 0..127
      int koff = kt + ((sg ^ (row & 7)) << 3);   // pre-swizzled source granule
      async16(Ah + (size_t)(bm + row) * lda + koff, &lA[inst * 512]);
      int brow = bn + row;
      if (brow > N - 1) brow = N - 1;
      async16(Bhi + (size_t)brow * ldb + koff, &lB[0][inst * 512]);
      if constexpr (TERMS == 2)
        async16(Blo + (size_t)brow * ldb + koff, &lB[TERMS - 1][inst * 512]);
    }
    asm volatile("s_waitcnt vmcnt(0)" ::: "memory");
    __syncthreads();

#pragma unroll
    for (int ks = 0; ks < 2; ++ks) {
      f16x8 ah[4], b0v[4], b1v[4];
#pragma unroll
      for (int mi = 0; mi < 4; ++mi) {
        int row = wm + mi * 16 + lrow;
        int off = row * 128 + ((ks * 64 + kgrp * 16) ^ ((row & 7) << 4));
        ah[mi] = *(const f16x8*)((const char*)lA + off);
      }
#pragma unroll
      for (int ni = 0; ni < 4; ++ni) {
        int row = wn + ni * 16 + lrow;
        int off = row * 128 + ((ks * 64 + kgrp * 16) ^ ((row & 7) << 4));
        b0v[ni] = *(const f16x8*)((const char*)lB[0] + off);
        if constexpr (TERMS == 2)
          b1v[ni] = *(const f16x8*)((const char*)lB[TERMS - 1] + off);
      }
#pragma unroll
      for (int mi = 0; mi < 4; ++mi)
#pragma unroll
        for (int ni = 0; ni < 4; ++ni) {
          acc[mi][ni] = MFMAH(ah[mi], b0v[ni], acc[mi][ni]);
          if constexpr (TERMS == 2)
            acc[mi][ni] = MFMAH(ah[mi], b1v[ni], acc[mi][ni]);
        }
    }
    __syncthreads();
  }

#pragma unroll
  for (int mi = 0; mi < 4; ++mi) {
#pragma unroll
    for (int ni = 0; ni < 4; ++ni) {
      int col = bn + wn + ni * 16 + lrow;
      float bv = (col < bsplit) ? bias[col] : bias2[col - bsplit];
      int row0 = bm + wm + mi * 16 + kgrp * 4;
      if constexpr (MODE == 0) {
#pragma unroll
        for (int r = 0; r < 4; ++r)
          ((float*)out0)[(size_t)(row0 + r) * ldc + col] = acc[mi][ni][r] + bv;
      } else if constexpr (MODE == 3) {
#pragma unroll
        for (int r = 0; r < 4; ++r)
          ((u16*)out0)[(size_t)(row0 + r) * ldc + col] = f2h(acc[mi][ni][r] + bv);
      } else if constexpr (MODE == 7) {
        if (col < 1024) {  // content half of Qb
#pragma unroll
          for (int r = 0; r < 4; ++r) {
            int row = row0 + r;
            ((u16*)out0)[(((size_t)((row >> 9) * 16 + (col >> 6)) * 512 + (row & 511)) << 7)
                         + (col & 63)] = f2h(acc[mi][ni][r] + bv);
          }
        } else {  // rope half of Qb
          int cc = col - 1024, hh = cc >> 6, d = cc & 63, i2 = d >> 1;
          bool odd = d & 1;
#pragma unroll
          for (int r = 0; r < 4; ++r) {
            int row = row0 + r, s = row & 511;
            float vv = acc[mi][ni][r] + bv;
            float p = __shfl_xor(vv, 1, 64);
            float2 t2 = stab[s * 32 + i2];
            float o = odd ? (vv * t2.x + p * t2.y) : (vv * t2.x - p * t2.y);
            ((u16*)out0)[(((size_t)((row >> 9) * 16 + hh) * 512 + (row & 511)) << 7)
                         + 64 + d] = f2h(o);
          }
        }
      } else if constexpr (MODE == 6) {
        if (col < 1024) {  // content half of Kb
#pragma unroll
          for (int r = 0; r < 4; ++r) {
            int row = row0 + r;
            ((u16*)out0)[(((size_t)((row >> 9) * 16 + (col >> 6)) * 512 + (row & 511)) << 7)
                         + (col & 63)] = f2h(acc[mi][ni][r] + bv);
          }
        } else if (col < 2048) {  // Vt [bh][d][s] transposed, 4 s packed
          int cc = col - 1024;
          u16 h0 = f2h(acc[mi][ni][0] + bv), h1 = f2h(acc[mi][ni][1] + bv);
          u16 h2 = f2h(acc[mi][ni][2] + bv), h3 = f2h(acc[mi][ni][3] + bv);
          uint2 pk;
          pk.x = (u32)h0 | ((u32)h1 << 16);
          pk.y = (u32)h2 | ((u32)h3 << 16);
          size_t base = ((size_t)((row0 >> 9) * 16 + (cc >> 6)) * 64 + (cc & 63)) * 512
                        + (row0 & 511);
          *reinterpret_cast<uint2*>((u16*)out1 + base) = pk;
        } else {  // k_r pre-rope f32, ld 128
#pragma unroll
          for (int r = 0; r < 4; ++r)
            ((float*)out2)[(size_t)(row0 + r) * 128 + (col - 2048)] = acc[mi][ni][r] + bv;
        }
      }
    }
  }
}

// ---------------- rope on k_r -> broadcast into Kb[...,64:128] (f16) ----------------
__global__ void ropek_kernel(const float* __restrict__ kr, const float2* __restrict__ stab,
                             u16* __restrict__ Kb) {
  int idx = blockIdx.x * 256 + threadIdx.x;  // 8192*32
  int t = idx >> 5, i = idx & 31;
  float vx = kr[(size_t)t * 128 + 2 * i], vy = kr[(size_t)t * 128 + 2 * i + 1];
  float2 t2 = stab[(t & 511) * 32 + i];
  float o0 = vx * t2.x - vy * t2.y;
  float o1 = vy * t2.x + vx * t2.y;
  u32 pk = (u32)f2h(o0) | ((u32)f2h(o1) << 16);
  int bb = t >> 9, ss = t & 511;
  size_t base = (size_t)bb * 16 * 512 * 128;
#pragma unroll
  for (int hh = 0; hh < 16; ++hh)
    *reinterpret_cast<u32*>(Kb + base + ((size_t)(hh * 512 + ss)) * 128 + 64 + 2 * i) = pk;
}

// ---------------- fused flash attention per (b,h, 64-row q tile) ----------------
// logits in log2 domain: s' = S*scale*log2e + maskbias
__global__ __launch_bounds__(256, 3) void attn_kernel(
    const u16* __restrict__ Qb, const u16* __restrict__ Kb, const u16* __restrict__ Vt,
    const int* __restrict__ mask, u16* __restrict__ ctx,
    float scale2) {
  __shared__ u16 sQ[64 * 128];
  __shared__ u16 sK[64 * 128];
  __shared__ u16 sV[64 * 64];
  __shared__ u16 sP[4][1024];  // PV A-fragment-ordered P per wave
  const int tid = threadIdx.x, wave = tid >> 6, lane = tid & 63;
  const int lrow = lane & 15, kgrp = lane >> 4;
  const int bh = blockIdx.x, b = bh >> 4, h = bh & 15;
  const int q0 = blockIdx.y * 64;
  const size_t qkbase = (size_t)bh * 512 * 128;
  const size_t vbase = (size_t)bh * 64 * 512;
  u16* __restrict__ sPw = sP[wave];

  // fragment-ordered P store offsets: element P[q=qp][k=nf*16+lrow] lands at
  // frag slot (ks*64 + kg*16 + q)*8 + j with ks=k>>5, kg=(k>>3)&3, j=k&7
  u32 poff[4][4];
#pragma unroll
  for (int r = 0; r < 4; ++r) {
    int qp = kgrp * 4 + r;
#pragma unroll
    for (int nf = 0; nf < 4; ++nf)
      poff[r][nf] = (u32)((nf >> 1) * 512 + ((((nf & 1) << 1) | (lrow >> 3))) * 128
                          + qp * 8 + (lrow & 7));
  }

  {  // stage Q tile once (rows 256B = 16 granules, xor-swizzled source)
    int g = lane & 15, rr = lane >> 4;
#pragma unroll
    for (int ii = 0; ii < 4; ++ii) {
      int inst = wave * 4 + ii;
      int row = inst * 4 + rr;
      int perm = (g & 8) | ((g & 7) ^ (row & 7));
      async16(Qb + qkbase + (size_t)(q0 + row) * 128 + perm * 8, &sQ[inst * 512]);
    }
  }

  const f32x4 zero = {0.f, 0.f, 0.f, 0.f};
  f32x4 O[4];
#pragma unroll
  for (int nf = 0; nf < 4; ++nf) O[nf] = zero;
  float m_run[4], l_part[4];
#pragma unroll
  for (int r = 0; r < 4; ++r) { m_run[r] = -1e30f; l_part[r] = 0.f; }

  for (int kvt = 0; kvt < 8; ++kvt) {
    const int kv0 = kvt * 64;
    {
      int g = lane & 15, rr = lane >> 4;
#pragma unroll
      for (int ii = 0; ii < 4; ++ii) {
        int inst = wave * 4 + ii;
        int row = inst * 4 + rr;
        int perm = (g & 8) | ((g & 7) ^ (row & 7));
        async16(Kb + qkbase + (size_t)(kv0 + row) * 128 + perm * 8, &sK[inst * 512]);
      }
      int g2 = lane & 7, r2 = lane >> 3;
#pragma unroll
      for (int ii = 0; ii < 2; ++ii) {
        int inst = wave * 2 + ii;
        int row = inst * 8 + r2;
        async16(Vt + vbase + (size_t)row * 512 + kv0 + ((g2 ^ (row & 7)) << 3),
                &sV[inst * 512]);
      }
    }
    // mask -> additive bias while loads are in flight
    float mb[4];
#pragma unroll
    for (int nf = 0; nf < 4; ++nf)
      mb[nf] = (mask[b * 512 + kv0 + nf * 16 + lrow] != 0) ? 0.f : -1e30f;

    asm volatile("s_waitcnt vmcnt(0)" ::: "memory");
    __syncthreads();

    f32x4 S[4];
#pragma unroll
    for (int nf = 0; nf < 4; ++nf) S[nf] = zero;
#pragma unroll
    for (int ks = 0; ks < 4; ++ks) {
      int qrow = wave * 16 + lrow;
      int kb = ks * 64 + kgrp * 16;
      f16x8 aq = *(const f16x8*)((const char*)sQ + qrow * 256 + (kb ^ ((qrow & 7) << 4)));
#pragma unroll
      for (int nf = 0; nf < 4; ++nf) {
        int krow = nf * 16 + lrow;
        f16x8 bk = *(const f16x8*)((const char*)sK + krow * 256 + (kb ^ ((krow & 7) << 4)));
        S[nf] = MFMAH(aq, bk, S[nf]);
      }
    }

    float pvv[4][4];
    float tmax[4];
#pragma unroll
    for (int r = 0; r < 4; ++r) tmax[r] = -1e30f;
#pragma unroll
    for (int nf = 0; nf < 4; ++nf) {
#pragma unroll
      for (int r = 0; r < 4; ++r) {
        float v = fmaf(S[nf][r], scale2, mb[nf]);
        pvv[nf][r] = v;
        tmax[r] = fmaxf(tmax[r], v);
      }
    }
#pragma unroll
    for (int r = 0; r < 4; ++r) {
#pragma unroll
      for (int mv = 1; mv < 16; mv <<= 1)
        tmax[r] = fmaxf(tmax[r], __shfl_xor(tmax[r], mv, 64));
    }

    bool grow = (tmax[0] > m_run[0] + 8.f) || (tmax[1] > m_run[1] + 8.f) ||
                (tmax[2] > m_run[2] + 8.f) || (tmax[3] > m_run[3] + 8.f);
    if (__any(grow ? 1 : 0)) {
#pragma unroll
      for (int r = 0; r < 4; ++r) {
        float newm = fmaxf(m_run[r], tmax[r]);
        float sc = fexp2(m_run[r] - newm);
        m_run[r] = newm;
        float ts = 0.f;
#pragma unroll
        for (int nf = 0; nf < 4; ++nf) {
          float pe = fexp2(pvv[nf][r] - newm);
          sPw[poff[r][nf]] = f2h(pe);
          ts += pe;
        }
        l_part[r] = l_part[r] * sc + ts;
#pragma unroll
        for (int nf = 0; nf < 4; ++nf) O[nf][r] *= sc;
      }
    } else {  // defer-max fast path: P bounded by 2^8, no rescale
#pragma unroll
      for (int r = 0; r < 4; ++r) {
        float ts = 0.f;
#pragma unroll
        for (int nf = 0; nf < 4; ++nf) {
          float pe = fexp2(pvv[nf][r] - m_run[r]);
          sPw[poff[r][nf]] = f2h(pe);
          ts += pe;
        }
        l_part[r] += ts;
      }
    }

#pragma unroll
    for (int ks = 0; ks < 2; ++ks) {
      int kb = ks * 64 + kgrp * 16;
      f16x8 ap = *(const f16x8*)((const char*)sPw + ((ks * 64 + kgrp * 16 + lrow) << 4));
#pragma unroll
      for (int nf = 0; nf < 4; ++nf) {
        int vr = nf * 16 + lrow;
        f16x8 bv = *(const f16x8*)((const char*)sV + vr * 128 + (kb ^ ((vr & 7) << 4)));
        O[nf] = MFMAH(ap, bv, O[nf]);
      }
    }
    __syncthreads();
  }

  // one cross-lane reduce of the normalizer at the end
#pragma unroll
  for (int r = 0; r < 4; ++r) {
#pragma unroll
    for (int mv = 1; mv < 16; mv <<= 1) l_part[r] += __shfl_xor(l_part[r], mv, 64);
  }

#pragma unroll
  for (int r = 0; r < 4; ++r) {
    float inv = 1.0f / l_part[r];
    int trow = b * 512 + q0 + wave * 16 + kgrp * 4 + r;
#pragma unroll
    for (int nf = 0; nf < 4; ++nf) {
      int col = h * 64 + nf * 16 + lrow;
      ctx[(size_t)trow * 1024 + col] = f2h(O[nf][r] * inv);
    }
  }
}

// ---------------- launch ----------------
extern "C" void kernel_launch(void* const* d_in, const int* in_sizes, int n_in,
                              void* d_out, int out_size, void* d_ws, size_t ws_size,
                              hipStream_t stream) {
  const float* x     = (const float*)d_in[0];
  const int*   mask  = (const int*)d_in[1];
  const float* w_dkv = (const float*)d_in[2];
  const float* b_dkv = (const float*)d_in[3];
  const float* w_dq  = (const float*)d_in[4];
  const float* b_dq  = (const float*)d_in[5];
  const float* w_uq  = (const float*)d_in[6];
  const float* b_uq  = (const float*)d_in[7];
  const float* w_uk  = (const float*)d_in[8];
  const float* b_uk  = (const float*)d_in[9];
  const float* w_uv  = (const float*)d_in[10];
  const float* b_uv  = (const float*)d_in[11];
  const float* w_qr  = (const float*)d_in[12];
  const float* b_qr  = (const float*)d_in[13];
  const float* w_kr  = (const float*)d_in[14];
  const float* b_kr  = (const float*)d_in[15];
  const float* w_fc  = (const float*)d_in[16];
  const float* b_fc  = (const float*)d_in[17];
  float* out = (float*)d_out;

  char* ws = (char*)d_ws;
  size_t off = 0;
  auto alloc = [&](size_t bytes) -> void* {
    void* p = ws + off;
    off += (bytes + 255) & ~(size_t)255;
    return p;
  };
  u16* xh     = (u16*)alloc(33554432);   // [8192][2048] f16
  u16* WfTh   = (u16*)alloc(4194304);    // [1024][2048] f16
  u16* WfTl   = (u16*)alloc(4194304);
  u16* WqT    = (u16*)alloc(2097152);    // [2048][512]: uq rows 0..1023, qr 1024..2047
  u16* WkvT   = (u16*)alloc(2228224);    // [2176][512]: uk | uv | kr(padded 128)
  u16* WfcTh  = (u16*)alloc(4194304);    // [2048][1024]
  u16* WfcTl  = (u16*)alloc(4194304);
  u16* c      = (u16*)alloc(16777216);   // [8192][1024] f16 (reused as ctx)
  u16* Qb     = (u16*)alloc(33554432);   // [256][512][128] f16
  u16* Kb     = (u16*)alloc(33554432);
  u16* Vt     = (u16*)alloc(16777216);   // [256][64][512] f16
  float* krf  = (float*)alloc(4194304);  // [8192][128] f32 (cols 64..127 junk)
  float2* stab = (float2*)alloc(131072); // [512][32] {sin,cos}
  float* biasQ  = (float*)alloc(8192);   // [2048]
  float* biasKV = (float*)alloc(8704);   // [2176]
  u16* ctx = c;
  (void)ws_size; (void)in_sizes; (void)n_in; (void)out_size;

  const float scale = 1.0f / (sqrtf(128.0f) + sqrtf(64.0f));
  const float scale2 = scale * 1.4426950408889634f;  // log2(e) folded

  stab_kernel<<<64, 256, 0, stream>>>(stab);
  convert_x_kernel<<<16384, 256, 0, stream>>>(x, xh, 4194304);
  biascat_kernel<<<17, 256, 0, stream>>>(b_uq, b_qr, b_uk, b_uv, b_kr, biasQ, biasKV);
  wtrans_kernel<2><<<dim3(64, 16), 256, 0, stream>>>(w_dkv, 512, WfTh, WfTl, 0, 2048);
  wtrans_kernel<2><<<dim3(64, 16), 256, 0, stream>>>(w_dq, 512, WfTh, WfTl, 512, 2048);
  wtrans_kernel<1><<<dim3(16, 32), 256, 0, stream>>>(w_uq, 1024, WqT, nullptr, 0, 512);
  wtrans_kernel<1><<<dim3(16, 32), 256, 0, stream>>>(w_qr, 1024, WqT, nullptr, 1024, 512);
  wtrans_kernel<1><<<dim3(16, 32), 256, 0, stream>>>(w_uk, 1024, WkvT, nullptr, 0, 512);
  wtrans_kernel<1><<<dim3(16, 32), 256, 0, stream>>>(w_uv, 1024, WkvT, nullptr, 1024, 512);
  wtrans_kernel<1><<<dim3(16, 2), 256, 0, stream>>>(w_kr, 64, WkvT, nullptr, 2048, 512);
  wtrans_kernel<2><<<dim3(32, 64), 256, 0, stream>>>(w_fc, 2048, WfcTh, WfcTl, 0, 1024);

  // c = x @ [w_dkv | w_dq] + bias  -> f16 [8192][1024], B hi/lo 2-term
  gemmh_kernel<3, 2><<<dim3(64, 8), 256, 0, stream>>>(
      xh, 2048, WfTh, WfTl, 2048, b_dkv, b_dq, 512,
      (void*)c, nullptr, nullptr, nullptr, 1024, 2048, 1024);
  // q-side fused: [q_c | rope(q_r)] -> Qb
  gemmh_kernel<7, 1><<<dim3(64, 16), 256, 0, stream>>>(
      c + 512, 1024, WqT, nullptr, 512, biasQ, biasQ, 2048,
      (void*)Qb, nullptr, nullptr, stab, 2048, 512, 0);
  // kv-side fused: [k_c | v^T | k_r] -> Kb, Vt, krf
  gemmh_kernel<6, 1><<<dim3(64, 17), 256, 0, stream>>>(
      c, 1024, WkvT, nullptr, 512, biasKV, biasKV, 2176,
      (void*)Kb, (void*)Vt, (void*)krf, nullptr, 2176, 512, 0);

  ropek_kernel<<<1024, 256, 0, stream>>>(krf, stab, Kb);

  attn_kernel<<<dim3(256, 8), 256, 0, stream>>>(Qb, Kb, Vt, mask, ctx, scale2);

  // out = ctx @ w_fc + b_fc  -> f32 [8192][2048], B hi/lo 2-term
  gemmh_kernel<0, 2><<<dim3(64, 16), 256, 0, stream>>>(
      ctx, 1024, WfcTh, WfcTl, 1024, b_fc, b_fc, 2048,
      (void*)out, nullptr, nullptr, nullptr, 2048, 1024, 2048);
}

// Round 5
// 448.554 us; speedup vs baseline: 1.3205x; 1.0227x over previous
//
#include <hip/hip_runtime.h>
#include <cstdint>
#include <cmath>

typedef unsigned short u16;
typedef unsigned int   u32;
typedef _Float16 f16x8 __attribute__((ext_vector_type(8)));
typedef float f32x4  __attribute__((ext_vector_type(4)));

#define MFMAH(a, b, c) __builtin_amdgcn_mfma_f32_16x16x32_f16((a), (b), (c), 0, 0, 0)

__device__ __forceinline__ u16 f2h(float f) {
  _Float16 h = (_Float16)f;
  return __builtin_bit_cast(u16, h);
}
__device__ __forceinline__ float h2f(u16 u) {
  return (float)__builtin_bit_cast(_Float16, u);
}
__device__ __forceinline__ float fexp2(float x) { return __builtin_amdgcn_exp2f(x); }
__device__ __forceinline__ void async16(const void* g, void* l) {
  __builtin_amdgcn_global_load_lds((const __attribute__((address_space(1))) u32*)g,
                                   (__attribute__((address_space(3))) u32*)l, 16, 0, 0);
}

// ---------------- prep: sin/cos table + concatenated biases (one dispatch) ----------------
__global__ void prep_kernel(float2* __restrict__ stab,
                            const float* __restrict__ buq, const float* __restrict__ bqr,
                            const float* __restrict__ buk, const float* __restrict__ buv,
                            const float* __restrict__ bkr,
                            float* __restrict__ biasQ, float* __restrict__ biasKV) {
  int idx = blockIdx.x * 256 + threadIdx.x;
  if (idx < 16384) {
    int s = idx >> 5, i = idx & 31;
    float theta = exp2f((float)i * (-13.287712379549449f / 32.0f));  // 10000^(-i/32)
    float ang = (float)s * theta;
    stab[idx] = make_float2(sinf(ang), cosf(ang));
  }
  int j = idx - 16384;
  if (j >= 0 && j < 2048) biasQ[j] = (j < 1024) ? buq[j] : bqr[j - 1024];
  int k = idx - 18432;
  if (k >= 0 && k < 2176)
    biasKV[k] = (k < 1024) ? buk[k]
              : (k < 2048) ? buv[k - 1024]
              : (k < 2112) ? bkr[k - 2048] : 0.f;
}

// ---------------- prep: convert x to f16 ----------------
__global__ void convert_x_kernel(const float* __restrict__ x, u16* __restrict__ xh, int n4) {
  int i = blockIdx.x * blockDim.x + threadIdx.x;
  if (i >= n4) return;
  float4 v = reinterpret_cast<const float4*>(x)[i];
  uint2 p;
  p.x = (u32)f2h(v.x) | ((u32)f2h(v.y) << 16);
  p.y = (u32)f2h(v.z) | ((u32)f2h(v.w) << 16);
  reinterpret_cast<uint2*>(xh)[i] = p;
}

// ---------------- prep: batched transpose [K,N] f32 -> [N][K] f16 (hi[/lo]) ----------------
struct Wptrs { const float* w0; const float* w1; const float* w2; const float* w3; };
template <int NOUT>
__global__ void wtrans_kernel(Wptrs wp, int N,
                              u16* __restrict__ Thi, u16* __restrict__ Tlo,
                              int row_off0, int row_stride, int dst_ld) {
  __shared__ float tile[32][33];
  const float* W = (blockIdx.z == 0) ? wp.w0 : (blockIdx.z == 1) ? wp.w1
                 : (blockIdx.z == 2) ? wp.w2 : wp.w3;
  int row_off = row_off0 + blockIdx.z * row_stride;
  int k0 = blockIdx.x * 32, n0 = blockIdx.y * 32;
  int tx = threadIdx.x & 31, ty = threadIdx.x >> 5;  // 32 x 8
#pragma unroll
  for (int i = 0; i < 32; i += 8)
    tile[ty + i][tx] = W[(size_t)(k0 + ty + i) * N + n0 + tx];
  __syncthreads();
#pragma unroll
  for (int i = 0; i < 32; i += 8) {
    float v = tile[tx][ty + i];
    size_t o = (size_t)(row_off + n0 + ty + i) * dst_ld + k0 + tx;
    u16 h = f2h(v);
    Thi[o] = h;
    if constexpr (NOUT == 2) Tlo[o] = f2h(v - h2f(h));
  }
}

// ---------------- generic f16 GEMM ----------------
// C[M,N] = A[M,K] @ B^T-stored-[N,K] + bias
// TERMS==2: B split hi/lo (a*bh + a*bl).  TERMS==1: B single.
// MODE 0: f32 out (ldc).  MODE 3: f16 out (ldc).
// MODE 7: q-side fused: col<1024 -> Qb content; col>=1024 -> rope -> Qb[64:128].
// MODE 6: kv-side fused: col<1024 -> Kb content; col<2048 -> Vt [bh][d][s];
//         col>=2048 -> f32 krf (ld 128).
template <int MODE, int TERMS>
__global__ __launch_bounds__(256, TERMS == 2 ? 3 : 4) void gemmh_kernel(
    const u16* __restrict__ Ah, int lda,
    const u16* __restrict__ Bhi, const u16* __restrict__ Blo, int ldb,
    const float* __restrict__ bias, const float* __restrict__ bias2, int bsplit,
    void* __restrict__ out0, void* __restrict__ out1, void* __restrict__ out2,
    const float2* __restrict__ stab, int N, int K, int ldc) {
  __shared__ u16 lA[128 * 64];
  __shared__ u16 lB[TERMS][128 * 64];
  const int tid = threadIdx.x;
  const int wave = tid >> 6, lane = tid & 63;
  const int lrow = lane & 15, kgrp = lane >> 4;
  const int nwg = gridDim.x * gridDim.y;
  const int orig = blockIdx.y * gridDim.x + blockIdx.x;
  const int swz = (orig & 7) * (nwg >> 3) + (orig >> 3);
  const int bm = (swz % gridDim.x) * 128, bn = (swz / gridDim.x) * 128;
  const int wm = (wave >> 1) * 64, wn = (wave & 1) * 64;
  const int srow = lane >> 3, sg = lane & 7;

  f32x4 acc[4][4];
  const f32x4 zero = {0.f, 0.f, 0.f, 0.f};
#pragma unroll
  for (int i = 0; i < 4; ++i)
#pragma unroll
    for (int j = 0; j < 4; ++j) acc[i][j] = zero;

  for (int kt = 0; kt < K; kt += 64) {
#pragma unroll
    for (int ii = 0; ii < 4; ++ii) {
      int inst = wave * 4 + ii;
      int row = inst * 8 + srow;
      int koff = kt + ((sg ^ (row & 7)) << 3);
      async16(Ah + (size_t)(bm + row) * lda + koff, &lA[inst * 512]);
      int brow = bn + row;
      if (brow > N - 1) brow = N - 1;
      async16(Bhi + (size_t)brow * ldb + koff, &lB[0][inst * 512]);
      if constexpr (TERMS == 2)
        async16(Blo + (size_t)brow * ldb + koff, &lB[TERMS - 1][inst * 512]);
    }
    asm volatile("s_waitcnt vmcnt(0)" ::: "memory");
    __syncthreads();

#pragma unroll
    for (int ks = 0; ks < 2; ++ks) {
      f16x8 ah[4], b0v[4], b1v[4];
#pragma unroll
      for (int mi = 0; mi < 4; ++mi) {
        int row = wm + mi * 16 + lrow;
        int off = row * 128 + ((ks * 64 + kgrp * 16) ^ ((row & 7) << 4));
        ah[mi] = *(const f16x8*)((const char*)lA + off);
      }
#pragma unroll
      for (int ni = 0; ni < 4; ++ni) {
        int row = wn + ni * 16 + lrow;
        int off = row * 128 + ((ks * 64 + kgrp * 16) ^ ((row & 7) << 4));
        b0v[ni] = *(const f16x8*)((const char*)lB[0] + off);
        if constexpr (TERMS == 2)
          b1v[ni] = *(const f16x8*)((const char*)lB[TERMS - 1] + off);
      }
#pragma unroll
      for (int mi = 0; mi < 4; ++mi)
#pragma unroll
        for (int ni = 0; ni < 4; ++ni) {
          acc[mi][ni] = MFMAH(ah[mi], b0v[ni], acc[mi][ni]);
          if constexpr (TERMS == 2)
            acc[mi][ni] = MFMAH(ah[mi], b1v[ni], acc[mi][ni]);
        }
    }
    __syncthreads();
  }

#pragma unroll
  for (int mi = 0; mi < 4; ++mi) {
#pragma unroll
    for (int ni = 0; ni < 4; ++ni) {
      int col = bn + wn + ni * 16 + lrow;
      float bv = (col < bsplit) ? bias[col] : bias2[col - bsplit];
      int row0 = bm + wm + mi * 16 + kgrp * 4;
      if constexpr (MODE == 0) {
#pragma unroll
        for (int r = 0; r < 4; ++r)
          ((float*)out0)[(size_t)(row0 + r) * ldc + col] = acc[mi][ni][r] + bv;
      } else if constexpr (MODE == 3) {
#pragma unroll
        for (int r = 0; r < 4; ++r)
          ((u16*)out0)[(size_t)(row0 + r) * ldc + col] = f2h(acc[mi][ni][r] + bv);
      } else if constexpr (MODE == 7) {
        if (col < 1024) {
#pragma unroll
          for (int r = 0; r < 4; ++r) {
            int row = row0 + r;
            ((u16*)out0)[(((size_t)((row >> 9) * 16 + (col >> 6)) * 512 + (row & 511)) << 7)
                         + (col & 63)] = f2h(acc[mi][ni][r] + bv);
          }
        } else {
          int cc = col - 1024, hh = cc >> 6, d = cc & 63, i2 = d >> 1;
          bool odd = d & 1;
#pragma unroll
          for (int r = 0; r < 4; ++r) {
            int row = row0 + r, s = row & 511;
            float vv = acc[mi][ni][r] + bv;
            float p = __shfl_xor(vv, 1, 64);
            float2 t2 = stab[s * 32 + i2];
            float o = odd ? (vv * t2.x + p * t2.y) : (vv * t2.x - p * t2.y);
            ((u16*)out0)[(((size_t)((row >> 9) * 16 + hh) * 512 + (row & 511)) << 7)
                         + 64 + d] = f2h(o);
          }
        }
      } else if constexpr (MODE == 6) {
        if (col < 1024) {
#pragma unroll
          for (int r = 0; r < 4; ++r) {
            int row = row0 + r;
            ((u16*)out0)[(((size_t)((row >> 9) * 16 + (col >> 6)) * 512 + (row & 511)) << 7)
                         + (col & 63)] = f2h(acc[mi][ni][r] + bv);
          }
        } else if (col < 2048) {
          int cc = col - 1024;
          u16 h0 = f2h(acc[mi][ni][0] + bv), h1 = f2h(acc[mi][ni][1] + bv);
          u16 h2 = f2h(acc[mi][ni][2] + bv), h3 = f2h(acc[mi][ni][3] + bv);
          uint2 pk2;
          pk2.x = (u32)h0 | ((u32)h1 << 16);
          pk2.y = (u32)h2 | ((u32)h3 << 16);
          size_t base = ((size_t)((row0 >> 9) * 16 + (cc >> 6)) * 64 + (cc & 63)) * 512
                        + (row0 & 511);
          *reinterpret_cast<uint2*>((u16*)out1 + base) = pk2;
        } else {
#pragma unroll
          for (int r = 0; r < 4; ++r)
            ((float*)out2)[(size_t)(row0 + r) * 128 + (col - 2048)] = acc[mi][ni][r] + bv;
        }
      }
    }
  }
}

// ---------------- rope on k_r -> broadcast into Kb[...,64:128] (f16) ----------------
__global__ void ropek_kernel(const float* __restrict__ kr, const float2* __restrict__ stab,
                             u16* __restrict__ Kb) {
  int idx = blockIdx.x * 256 + threadIdx.x;  // 8192*32
  int t = idx >> 5, i = idx & 31;
  float vx = kr[(size_t)t * 128 + 2 * i], vy = kr[(size_t)t * 128 + 2 * i + 1];
  float2 t2 = stab[(t & 511) * 32 + i];
  float o0 = vx * t2.x - vy * t2.y;
  float o1 = vy * t2.x + vx * t2.y;
  u32 pk2 = (u32)f2h(o0) | ((u32)f2h(o1) << 16);
  int bb = t >> 9, ss = t & 511;
  size_t base = (size_t)bb * 16 * 512 * 128;
#pragma unroll
  for (int hh = 0; hh < 16; ++hh)
    *reinterpret_cast<u32*>(Kb + base + ((size_t)(hh * 512 + ss)) * 128 + 64 + 2 * i) = pk2;
}

// ---------------- fused flash attention: swapped QK^T, in-register softmax ----------------
// S^T = mfma(K,Q): lane holds P[k = nf*16 + g*4 + r][q = wave*16 + (lane&15)].
// Row-max/sum are lane-local; P reaches PV A-frags via 4-lane-group shfls. No P LDS.
__global__ __launch_bounds__(256, 4) void attn_kernel(
    const u16* __restrict__ Qb, const u16* __restrict__ Kb, const u16* __restrict__ Vt,
    const int* __restrict__ mask, u16* __restrict__ ctx,
    float scale2) {
  __shared__ u16 sQ[64 * 128];
  __shared__ u16 sK[64 * 128];
  __shared__ u16 sV[64 * 64];   // total 40 KiB -> 4 blocks/CU
  const int tid = threadIdx.x, wave = tid >> 6, lane = tid & 63;
  const int lrow = lane & 15, g = lane >> 4;
  const int bh = blockIdx.x, b = bh >> 4, h = bh & 15;
  const int q0 = blockIdx.y * 64;
  const size_t qkbase = (size_t)bh * 512 * 128;
  const size_t vbase = (size_t)bh * 64 * 512;

  {  // stage Q tile once
    int gg = lane & 15, rr = lane >> 4;
#pragma unroll
    for (int ii = 0; ii < 4; ++ii) {
      int inst = wave * 4 + ii;
      int row = inst * 4 + rr;
      int perm = (gg & 8) | ((gg & 7) ^ (row & 7));
      async16(Qb + qkbase + (size_t)(q0 + row) * 128 + perm * 8, &sQ[inst * 512]);
    }
  }

  const f32x4 zero = {0.f, 0.f, 0.f, 0.f};
  f32x4 O[4];
#pragma unroll
  for (int nf = 0; nf < 4; ++nf) O[nf] = zero;
  float m_run = -1e30f, lsum = 0.f;

  const int laneA = lrow + ((lane & 16) << 1);  // lrow + 32*(g&1)
  const int laneB = laneA + 16;
  const bool sel = (lane & 32) != 0;            // g>>1

  for (int kvt = 0; kvt < 8; ++kvt) {
    const int kv0 = kvt * 64;
    {
      int gg = lane & 15, rr = lane >> 4;
#pragma unroll
      for (int ii = 0; ii < 4; ++ii) {
        int inst = wave * 4 + ii;
        int row = inst * 4 + rr;
        int perm = (gg & 8) | ((gg & 7) ^ (row & 7));
        async16(Kb + qkbase + (size_t)(kv0 + row) * 128 + perm * 8, &sK[inst * 512]);
      }
      int g2 = lane & 7, r2 = lane >> 3;
#pragma unroll
      for (int ii = 0; ii < 2; ++ii) {
        int inst = wave * 2 + ii;
        int row = inst * 8 + r2;
        async16(Vt + vbase + (size_t)row * 512 + kv0 + ((g2 ^ (row & 7)) << 3),
                &sV[inst * 512]);
      }
    }
    // per-k mask bias while loads are in flight (k = kv0 + nf*16 + g*4 + r)
    float mb[4][4];
#pragma unroll
    for (int nf = 0; nf < 4; ++nf) {
      int4 mk = *reinterpret_cast<const int4*>(&mask[b * 512 + kv0 + nf * 16 + g * 4]);
      mb[nf][0] = mk.x ? 0.f : -1e30f;
      mb[nf][1] = mk.y ? 0.f : -1e30f;
      mb[nf][2] = mk.z ? 0.f : -1e30f;
      mb[nf][3] = mk.w ? 0.f : -1e30f;
    }

    asm volatile("s_waitcnt vmcnt(0)" ::: "memory");
    __syncthreads();

    // S^T[nf] = K_nf x Q  (swapped operands; same LDS fragment reads)
    f32x4 S[4];
#pragma unroll
    for (int nf = 0; nf < 4; ++nf) S[nf] = zero;
#pragma unroll
    for (int ks = 0; ks < 4; ++ks) {
      int qrow = wave * 16 + lrow;
      int kb = ks * 64 + g * 16;
      f16x8 bq = *(const f16x8*)((const char*)sQ + qrow * 256 + (kb ^ ((qrow & 7) << 4)));
#pragma unroll
      for (int nf = 0; nf < 4; ++nf) {
        int krow = nf * 16 + lrow;
        f16x8 ak = *(const f16x8*)((const char*)sK + krow * 256 + (kb ^ ((krow & 7) << 4)));
        S[nf] = MFMAH(ak, bq, S[nf]);
      }
    }

    float pvv[4][4];
    float tm = -1e30f;
#pragma unroll
    for (int nf = 0; nf < 4; ++nf) {
#pragma unroll
      for (int r = 0; r < 4; ++r) {
        float v = fmaf(S[nf][r], scale2, mb[nf][r]);
        pvv[nf][r] = v;
        tm = fmaxf(tm, v);
      }
    }
    tm = fmaxf(tm, __shfl_xor(tm, 16, 64));
    tm = fmaxf(tm, __shfl_xor(tm, 32, 64));

    u32 pk[4][2];
    float ts = 0.f;
    bool grow = tm > m_run + 8.f;
    if (__any(grow ? 1 : 0)) {
      float newm = fmaxf(m_run, tm);
      float sc = fexp2(m_run - newm);
      m_run = newm;
#pragma unroll
      for (int nf = 0; nf < 4; ++nf) {
        float e0 = fexp2(pvv[nf][0] - newm), e1 = fexp2(pvv[nf][1] - newm);
        float e2 = fexp2(pvv[nf][2] - newm), e3 = fexp2(pvv[nf][3] - newm);
        ts += (e0 + e1) + (e2 + e3);
        pk[nf][0] = (u32)f2h(e0) | ((u32)f2h(e1) << 16);
        pk[nf][1] = (u32)f2h(e2) | ((u32)f2h(e3) << 16);
      }
      lsum = lsum * sc + ts;
      float scq[4];
#pragma unroll
      for (int r = 0; r < 4; ++r) scq[r] = __shfl(sc, g * 4 + r, 64);
#pragma unroll
      for (int nf = 0; nf < 4; ++nf)
#pragma unroll
        for (int r = 0; r < 4; ++r) O[nf][r] *= scq[r];
    } else {  // defer-max fast path (P bounded by 2^8)
#pragma unroll
      for (int nf = 0; nf < 4; ++nf) {
        float e0 = fexp2(pvv[nf][0] - m_run), e1 = fexp2(pvv[nf][1] - m_run);
        float e2 = fexp2(pvv[nf][2] - m_run), e3 = fexp2(pvv[nf][3] - m_run);
        ts += (e0 + e1) + (e2 + e3);
        pk[nf][0] = (u32)f2h(e0) | ((u32)f2h(e1) << 16);
        pk[nf][1] = (u32)f2h(e2) | ((u32)f2h(e3) << 16);
      }
      lsum += ts;
    }

    // exchange P within 4-lane column groups -> PV A-frags, then PV MFMA
#pragma unroll
    for (int ks = 0; ks < 2; ++ks) {
      int n0 = 2 * ks, n1 = 2 * ks + 1;
      u32 w0a = (u32)__shfl((int)pk[n0][0], laneA, 64);
      u32 w0b = (u32)__shfl((int)pk[n1][0], laneA, 64);
      u32 w1a = (u32)__shfl((int)pk[n0][1], laneA, 64);
      u32 w1b = (u32)__shfl((int)pk[n1][1], laneA, 64);
      u32 w2a = (u32)__shfl((int)pk[n0][0], laneB, 64);
      u32 w2b = (u32)__shfl((int)pk[n1][0], laneB, 64);
      u32 w3a = (u32)__shfl((int)pk[n0][1], laneB, 64);
      u32 w3b = (u32)__shfl((int)pk[n1][1], laneB, 64);
      union { u32 w[4]; f16x8 v; } ap;
      ap.w[0] = sel ? w0b : w0a;
      ap.w[1] = sel ? w1b : w1a;
      ap.w[2] = sel ? w2b : w2a;
      ap.w[3] = sel ? w3b : w3a;
      int kb = ks * 64 + g * 16;
#pragma unroll
      for (int nf = 0; nf < 4; ++nf) {
        int vr = nf * 16 + lrow;
        f16x8 bv = *(const f16x8*)((const char*)sV + vr * 128 + (kb ^ ((vr & 7) << 4)));
        O[nf] = MFMAH(ap.v, bv, O[nf]);
      }
    }
    __syncthreads();
  }

  // final: reduce l across 4-lane groups, redistribute to O's q-rows
  lsum += __shfl_xor(lsum, 16, 64);
  lsum += __shfl_xor(lsum, 32, 64);
  float linv[4];
#pragma unroll
  for (int r = 0; r < 4; ++r) linv[r] = 1.0f / __shfl(lsum, g * 4 + r, 64);

#pragma unroll
  for (int r = 0; r < 4; ++r) {
    int trow = b * 512 + q0 + wave * 16 + g * 4 + r;
#pragma unroll
    for (int nf = 0; nf < 4; ++nf) {
      int col = h * 64 + nf * 16 + lrow;
      ctx[(size_t)trow * 1024 + col] = f2h(O[nf][r] * linv[r]);
    }
  }
}

// ---------------- launch ----------------
extern "C" void kernel_launch(void* const* d_in, const int* in_sizes, int n_in,
                              void* d_out, int out_size, void* d_ws, size_t ws_size,
                              hipStream_t stream) {
  const float* x     = (const float*)d_in[0];
  const int*   mask  = (const int*)d_in[1];
  const float* w_dkv = (const float*)d_in[2];
  const float* b_dkv = (const float*)d_in[3];
  const float* w_dq  = (const float*)d_in[4];
  const float* b_dq  = (const float*)d_in[5];
  const float* w_uq  = (const float*)d_in[6];
  const float* b_uq  = (const float*)d_in[7];
  const float* w_uk  = (const float*)d_in[8];
  const float* b_uk  = (const float*)d_in[9];
  const float* w_uv  = (const float*)d_in[10];
  const float* b_uv  = (const float*)d_in[11];
  const float* w_qr  = (const float*)d_in[12];
  const float* b_qr  = (const float*)d_in[13];
  const float* w_kr  = (const float*)d_in[14];
  const float* b_kr  = (const float*)d_in[15];
  const float* w_fc  = (const float*)d_in[16];
  const float* b_fc  = (const float*)d_in[17];
  float* out = (float*)d_out;

  char* ws = (char*)d_ws;
  size_t off = 0;
  auto alloc = [&](size_t bytes) -> void* {
    void* p = ws + off;
    off += (bytes + 255) & ~(size_t)255;
    return p;
  };
  u16* xh     = (u16*)alloc(33554432);   // [8192][2048] f16
  u16* WfTh   = (u16*)alloc(4194304);    // [1024][2048] f16
  u16* WfTl   = (u16*)alloc(4194304);
  u16* WqT    = (u16*)alloc(2097152);    // [2048][512]: uq | qr
  u16* WkvT   = (u16*)alloc(2228224);    // [2176][512]: uk | uv | kr(pad 128)
  u16* WfcTh  = (u16*)alloc(4194304);    // [2048][1024]
  u16* WfcTl  = (u16*)alloc(4194304);
  u16* c      = (u16*)alloc(16777216);   // [8192][1024] f16 (reused as ctx)
  u16* Qb     = (u16*)alloc(33554432);   // [256][512][128] f16
  u16* Kb     = (u16*)alloc(33554432);
  u16* Vt     = (u16*)alloc(16777216);   // [256][64][512] f16
  float* krf  = (float*)alloc(4194304);  // [8192][128] f32 (cols 64..127 junk)
  float2* stab = (float2*)alloc(131072); // [512][32] {sin,cos}
  float* biasQ  = (float*)alloc(8192);
  float* biasKV = (float*)alloc(8704);
  u16* ctx = c;
  (void)ws_size; (void)in_sizes; (void)n_in; (void)out_size;

  const float scale = 1.0f / (sqrtf(128.0f) + sqrtf(64.0f));
  const float scale2 = scale * 1.4426950408889634f;  // log2(e) folded

  prep_kernel<<<81, 256, 0, stream>>>(stab, b_uq, b_qr, b_uk, b_uv, b_kr, biasQ, biasKV);
  convert_x_kernel<<<16384, 256, 0, stream>>>(x, xh, 4194304);
  {
    Wptrs wf{w_dkv, w_dq, nullptr, nullptr};
    wtrans_kernel<2><<<dim3(64, 16, 2), 256, 0, stream>>>(wf, 512, WfTh, WfTl, 0, 512, 2048);
    Wptrs wq{w_uq, w_qr, nullptr, nullptr};
    wtrans_kernel<1><<<dim3(16, 32, 2), 256, 0, stream>>>(wq, 1024, WqT, nullptr, 0, 1024, 512);
    Wptrs wkv{w_uk, w_uv, nullptr, nullptr};
    wtrans_kernel<1><<<dim3(16, 32, 2), 256, 0, stream>>>(wkv, 1024, WkvT, nullptr, 0, 1024, 512);
    Wptrs wkr{w_kr, nullptr, nullptr, nullptr};
    wtrans_kernel<1><<<dim3(16, 2, 1), 256, 0, stream>>>(wkr, 64, WkvT, nullptr, 2048, 0, 512);
    Wptrs wfc{w_fc, nullptr, nullptr, nullptr};
    wtrans_kernel<2><<<dim3(32, 64, 1), 256, 0, stream>>>(wfc, 2048, WfcTh, WfcTl, 0, 0, 1024);
  }

  // c = x @ [w_dkv | w_dq] + bias  -> f16 [8192][1024], B hi/lo 2-term
  gemmh_kernel<3, 2><<<dim3(64, 8), 256, 0, stream>>>(
      xh, 2048, WfTh, WfTl, 2048, b_dkv, b_dq, 512,
      (void*)c, nullptr, nullptr, nullptr, 1024, 2048, 1024);
  // q-side fused: [q_c | rope(q_r)] -> Qb
  gemmh_kernel<7, 1><<<dim3(64, 16), 256, 0, stream>>>(
      c + 512, 1024, WqT, nullptr, 512, biasQ, biasQ, 2048,
      (void*)Qb, nullptr, nullptr, stab, 2048, 512, 0);
  // kv-side fused: [k_c | v^T | k_r] -> Kb, Vt, krf
  gemmh_kernel<6, 1><<<dim3(64, 17), 256, 0, stream>>>(
      c, 1024, WkvT, nullptr, 512, biasKV, biasKV, 2176,
      (void*)Kb, (void*)Vt, (void*)krf, nullptr, 2176, 512, 0);

  ropek_kernel<<<1024, 256, 0, stream>>>(krf, stab, Kb);

  attn_kernel<<<dim3(256, 8), 256, 0, stream>>>(Qb, Kb, Vt, mask, ctx, scale2);

  // out = ctx @ w_fc + b_fc  -> f32 [8192][2048], B hi/lo 2-term
  gemmh_kernel<0, 2><<<dim3(64, 16), 256, 0, stream>>>(
      ctx, 1024, WfcTh, WfcTl, 1024, b_fc, b_fc, 2048,
      (void*)out, nullptr, nullptr, nullptr, 2048, 1024, 2048);
}

// Round 9
// 441.677 us; speedup vs baseline: 1.3411x; 1.0156x over previous
//
#include <hip/hip_runtime.h>
#include <cstdint>
#include <cmath>

typedef unsigned short u16;
typedef unsigned int   u32;
typedef _Float16 f16x8 __attribute__((ext_vector_type(8)));
typedef float f32x4  __attribute__((ext_vector_type(4)));

#define MFMAH(a, b, c) __builtin_amdgcn_mfma_f32_16x16x32_f16((a), (b), (c), 0, 0, 0)

__device__ __forceinline__ u16 f2h(float f) {
  _Float16 h = (_Float16)f;
  return __builtin_bit_cast(u16, h);
}
__device__ __forceinline__ float h2f(u16 u) {
  return (float)__builtin_bit_cast(_Float16, u);
}
__device__ __forceinline__ float fexp2(float x) { return __builtin_amdgcn_exp2f(x); }
__device__ __forceinline__ void async16(const void* g, void* l) {
  __builtin_amdgcn_global_load_lds((const __attribute__((address_space(1))) u32*)g,
                                   (__attribute__((address_space(3))) u32*)l, 16, 0, 0);
}

// ---------------- prep: sin/cos table + concatenated biases (one dispatch) ----------------
__global__ void prep_kernel(float2* __restrict__ stab,
                            const float* __restrict__ buq, const float* __restrict__ bqr,
                            const float* __restrict__ buk, const float* __restrict__ buv,
                            const float* __restrict__ bkr,
                            float* __restrict__ biasQ, float* __restrict__ biasKV) {
  int idx = blockIdx.x * 256 + threadIdx.x;
  if (idx < 16384) {
    int s = idx >> 5, i = idx & 31;
    float theta = exp2f((float)i * (-13.287712379549449f / 32.0f));  // 10000^(-i/32)
    float ang = (float)s * theta;
    stab[idx] = make_float2(sinf(ang), cosf(ang));
  }
  int j = idx - 16384;
  if (j >= 0 && j < 2048) biasQ[j] = (j < 1024) ? buq[j] : bqr[j - 1024];
  int k = idx - 18432;
  if (k >= 0 && k < 2176)
    biasKV[k] = (k < 1024) ? buk[k]
              : (k < 2048) ? buv[k - 1024]
              : (k < 2112) ? bkr[k - 2048] : 0.f;
}

// ---------------- prep: convert x to f16 ----------------
__global__ void convert_x_kernel(const float* __restrict__ x, u16* __restrict__ xh, int n4) {
  int i = blockIdx.x * blockDim.x + threadIdx.x;
  if (i >= n4) return;
  float4 v = reinterpret_cast<const float4*>(x)[i];
  uint2 p;
  p.x = (u32)f2h(v.x) | ((u32)f2h(v.y) << 16);
  p.y = (u32)f2h(v.z) | ((u32)f2h(v.w) << 16);
  reinterpret_cast<uint2*>(xh)[i] = p;
}

// ---------------- prep: batched transpose [K,N] f32 -> [N][K] f16 ----------------
struct Wptrs { const float* w0; const float* w1; const float* w2; const float* w3; };
__global__ void wtrans_kernel(Wptrs wp, int N, u16* __restrict__ Thi,
                              int row_off0, int row_stride, int dst_ld) {
  __shared__ float tile[32][33];
  const float* W = (blockIdx.z == 0) ? wp.w0 : (blockIdx.z == 1) ? wp.w1
                 : (blockIdx.z == 2) ? wp.w2 : wp.w3;
  int row_off = row_off0 + blockIdx.z * row_stride;
  int k0 = blockIdx.x * 32, n0 = blockIdx.y * 32;
  int tx = threadIdx.x & 31, ty = threadIdx.x >> 5;  // 32 x 8
#pragma unroll
  for (int i = 0; i < 32; i += 8)
    tile[ty + i][tx] = W[(size_t)(k0 + ty + i) * N + n0 + tx];
  __syncthreads();
#pragma unroll
  for (int i = 0; i < 32; i += 8)
    Thi[(size_t)(row_off + n0 + ty + i) * dst_ld + k0 + tx] = f2h(tile[tx][ty + i]);
}

// ---------------- generic f16 1-term GEMM ----------------
// C[M,N] = A[M,K] @ B^T-stored-[N,K] + bias
// MODE 0: f32 out (ldc).  MODE 3: f16 out (ldc).
// MODE 7: q-side fused: col<1024 -> Qb content; col>=1024 -> rope -> Qb[64:128].
// MODE 6: kv-side fused: col<1024 -> Kb content; col<2048 -> Vt [bh][d][s];
//         col in [2048,2112) -> rope-k + 16-head broadcast into Kb[64:128].
template <int MODE>
__global__ __launch_bounds__(256, 4) void gemmh_kernel(
    const u16* __restrict__ Ah, int lda,
    const u16* __restrict__ Bh, int ldb,
    const float* __restrict__ bias, const float* __restrict__ bias2, int bsplit,
    void* __restrict__ out0, void* __restrict__ out1,
    const float2* __restrict__ stab, int N, int K, int ldc) {
  __shared__ u16 lA[128 * 64];
  __shared__ u16 lB[128 * 64];
  const int tid = threadIdx.x;
  const int wave = tid >> 6, lane = tid & 63;
  const int lrow = lane & 15, kgrp = lane >> 4;
  const int nwg = gridDim.x * gridDim.y;
  const int orig = blockIdx.y * gridDim.x + blockIdx.x;
  const int swz = (orig & 7) * (nwg >> 3) + (orig >> 3);
  const int bm = (swz % gridDim.x) * 128, bn = (swz / gridDim.x) * 128;
  const int wm = (wave >> 1) * 64, wn = (wave & 1) * 64;
  const int srow = lane >> 3, sg = lane & 7;

  f32x4 acc[4][4];
  const f32x4 zero = {0.f, 0.f, 0.f, 0.f};
#pragma unroll
  for (int i = 0; i < 4; ++i)
#pragma unroll
    for (int j = 0; j < 4; ++j) acc[i][j] = zero;

  for (int kt = 0; kt < K; kt += 64) {
#pragma unroll
    for (int ii = 0; ii < 4; ++ii) {
      int inst = wave * 4 + ii;
      int row = inst * 8 + srow;
      int koff = kt + ((sg ^ (row & 7)) << 3);
      async16(Ah + (size_t)(bm + row) * lda + koff, &lA[inst * 512]);
      int brow = bn + row;
      if (brow > N - 1) brow = N - 1;
      async16(Bh + (size_t)brow * ldb + koff, &lB[inst * 512]);
    }
    asm volatile("s_waitcnt vmcnt(0)" ::: "memory");
    __syncthreads();

#pragma unroll
    for (int ks = 0; ks < 2; ++ks) {
      f16x8 ah[4], bv[4];
#pragma unroll
      for (int mi = 0; mi < 4; ++mi) {
        int row = wm + mi * 16 + lrow;
        int off = row * 128 + ((ks * 64 + kgrp * 16) ^ ((row & 7) << 4));
        ah[mi] = *(const f16x8*)((const char*)lA + off);
      }
#pragma unroll
      for (int ni = 0; ni < 4; ++ni) {
        int row = wn + ni * 16 + lrow;
        int off = row * 128 + ((ks * 64 + kgrp * 16) ^ ((row & 7) << 4));
        bv[ni] = *(const f16x8*)((const char*)lB + off);
      }
#pragma unroll
      for (int mi = 0; mi < 4; ++mi)
#pragma unroll
        for (int ni = 0; ni < 4; ++ni)
          acc[mi][ni] = MFMAH(ah[mi], bv[ni], acc[mi][ni]);
    }
    __syncthreads();
  }

#pragma unroll
  for (int mi = 0; mi < 4; ++mi) {
#pragma unroll
    for (int ni = 0; ni < 4; ++ni) {
      int col = bn + wn + ni * 16 + lrow;
      float bv2 = (col < bsplit) ? bias[col] : bias2[col - bsplit];
      int row0 = bm + wm + mi * 16 + kgrp * 4;
      if constexpr (MODE == 0) {
#pragma unroll
        for (int r = 0; r < 4; ++r)
          ((float*)out0)[(size_t)(row0 + r) * ldc + col] = acc[mi][ni][r] + bv2;
      } else if constexpr (MODE == 3) {
#pragma unroll
        for (int r = 0; r < 4; ++r)
          ((u16*)out0)[(size_t)(row0 + r) * ldc + col] = f2h(acc[mi][ni][r] + bv2);
      } else if constexpr (MODE == 7) {
        if (col < 1024) {
#pragma unroll
          for (int r = 0; r < 4; ++r) {
            int row = row0 + r;
            ((u16*)out0)[(((size_t)((row >> 9) * 16 + (col >> 6)) * 512 + (row & 511)) << 7)
                         + (col & 63)] = f2h(acc[mi][ni][r] + bv2);
          }
        } else {
          int cc = col - 1024, hh = cc >> 6, d = cc & 63, i2 = d >> 1;
          bool odd = d & 1;
#pragma unroll
          for (int r = 0; r < 4; ++r) {
            int row = row0 + r, s = row & 511;
            float vv = acc[mi][ni][r] + bv2;
            float p = __shfl_xor(vv, 1, 64);
            float2 t2 = stab[s * 32 + i2];
            float o = odd ? (vv * t2.x + p * t2.y) : (vv * t2.x - p * t2.y);
            ((u16*)out0)[(((size_t)((row >> 9) * 16 + hh) * 512 + (row & 511)) << 7)
                         + 64 + d] = f2h(o);
          }
        }
      } else if constexpr (MODE == 6) {
        if (col < 1024) {
#pragma unroll
          for (int r = 0; r < 4; ++r) {
            int row = row0 + r;
            ((u16*)out0)[(((size_t)((row >> 9) * 16 + (col >> 6)) * 512 + (row & 511)) << 7)
                         + (col & 63)] = f2h(acc[mi][ni][r] + bv2);
          }
        } else if (col < 2048) {
          int cc = col - 1024;
          u16 h0 = f2h(acc[mi][ni][0] + bv2), h1 = f2h(acc[mi][ni][1] + bv2);
          u16 h2 = f2h(acc[mi][ni][2] + bv2), h3 = f2h(acc[mi][ni][3] + bv2);
          uint2 pk2;
          pk2.x = (u32)h0 | ((u32)h1 << 16);
          pk2.y = (u32)h2 | ((u32)h3 << 16);
          size_t base = ((size_t)((row0 >> 9) * 16 + (cc >> 6)) * 64 + (cc & 63)) * 512
                        + (row0 & 511);
          *reinterpret_cast<uint2*>((u16*)out1 + base) = pk2;
        } else if (col < 2112) {  // rope-k + broadcast to all 16 heads of Kb
          int d = col - 2048, i2 = d >> 1;
          bool odd = d & 1;
#pragma unroll
          for (int r = 0; r < 4; ++r) {
            int row = row0 + r, s = row & 511;
            float vv = acc[mi][ni][r] + bv2;
            float p = __shfl_xor(vv, 1, 64);
            float2 t2 = stab[s * 32 + i2];
            float o = odd ? (vv * t2.x + p * t2.y) : (vv * t2.x - p * t2.y);
            u16 oh = f2h(o);
            size_t base = (size_t)(row >> 9) * 16 * 512 * 128;
#pragma unroll
            for (int hh = 0; hh < 16; ++hh)
              ((u16*)out0)[base + ((size_t)(hh * 512 + s) << 7) + 64 + d] = oh;
          }
        }
      }
    }
  }
}

// ---------------- fused flash attention: swapped QK^T, in-register softmax ----------------
__global__ __launch_bounds__(256, 4) void attn_kernel(
    const u16* __restrict__ Qb, const u16* __restrict__ Kb, const u16* __restrict__ Vt,
    const int* __restrict__ mask, u16* __restrict__ ctx,
    float scale2) {
  __shared__ u16 sQ[64 * 128];
  __shared__ u16 sK[64 * 128];
  __shared__ u16 sV[64 * 64];   // total 40 KiB -> 4 blocks/CU
  const int tid = threadIdx.x, wave = tid >> 6, lane = tid & 63;
  const int lrow = lane & 15, g = lane >> 4;
  const int bh = blockIdx.x, b = bh >> 4, h = bh & 15;
  const int q0 = blockIdx.y * 64;
  const size_t qkbase = (size_t)bh * 512 * 128;
  const size_t vbase = (size_t)bh * 64 * 512;

  {  // stage Q tile once
    int gg = lane & 15, rr = lane >> 4;
#pragma unroll
    for (int ii = 0; ii < 4; ++ii) {
      int inst = wave * 4 + ii;
      int row = inst * 4 + rr;
      int perm = (gg & 8) | ((gg & 7) ^ (row & 7));
      async16(Qb + qkbase + (size_t)(q0 + row) * 128 + perm * 8, &sQ[inst * 512]);
    }
  }

  const f32x4 zero = {0.f, 0.f, 0.f, 0.f};
  f32x4 O[4];
#pragma unroll
  for (int nf = 0; nf < 4; ++nf) O[nf] = zero;
  float m_run = -1e30f, lsum = 0.f;

  const int laneA = lrow + ((lane & 16) << 1);  // lrow + 32*(g&1)
  const int laneB = laneA + 16;
  const bool sel = (lane & 32) != 0;            // g>>1

  for (int kvt = 0; kvt < 8; ++kvt) {
    const int kv0 = kvt * 64;
    {
      int gg = lane & 15, rr = lane >> 4;
#pragma unroll
      for (int ii = 0; ii < 4; ++ii) {
        int inst = wave * 4 + ii;
        int row = inst * 4 + rr;
        int perm = (gg & 8) | ((gg & 7) ^ (row & 7));
        async16(Kb + qkbase + (size_t)(kv0 + row) * 128 + perm * 8, &sK[inst * 512]);
      }
      int g2 = lane & 7, r2 = lane >> 3;
#pragma unroll
      for (int ii = 0; ii < 2; ++ii) {
        int inst = wave * 2 + ii;
        int row = inst * 8 + r2;
        async16(Vt + vbase + (size_t)row * 512 + kv0 + ((g2 ^ (row & 7)) << 3),
                &sV[inst * 512]);
      }
    }
    float mb[4][4];
#pragma unroll
    for (int nf = 0; nf < 4; ++nf) {
      int4 mk = *reinterpret_cast<const int4*>(&mask[b * 512 + kv0 + nf * 16 + g * 4]);
      mb[nf][0] = mk.x ? 0.f : -1e30f;
      mb[nf][1] = mk.y ? 0.f : -1e30f;
      mb[nf][2] = mk.z ? 0.f : -1e30f;
      mb[nf][3] = mk.w ? 0.f : -1e30f;
    }

    asm volatile("s_waitcnt vmcnt(0)" ::: "memory");
    __syncthreads();

    f32x4 S[4];
#pragma unroll
    for (int nf = 0; nf < 4; ++nf) S[nf] = zero;
#pragma unroll
    for (int ks = 0; ks < 4; ++ks) {
      int qrow = wave * 16 + lrow;
      int kb = ks * 64 + g * 16;
      f16x8 bq = *(const f16x8*)((const char*)sQ + qrow * 256 + (kb ^ ((qrow & 7) << 4)));
#pragma unroll
      for (int nf = 0; nf < 4; ++nf) {
        int krow = nf * 16 + lrow;
        f16x8 ak = *(const f16x8*)((const char*)sK + krow * 256 + (kb ^ ((krow & 7) << 4)));
        S[nf] = MFMAH(ak, bq, S[nf]);
      }
    }

    float pvv[4][4];
    float tm = -1e30f;
#pragma unroll
    for (int nf = 0; nf < 4; ++nf) {
#pragma unroll
      for (int r = 0; r < 4; ++r) {
        float v = fmaf(S[nf][r], scale2, mb[nf][r]);
        pvv[nf][r] = v;
        tm = fmaxf(tm, v);
      }
    }
    tm = fmaxf(tm, __shfl_xor(tm, 16, 64));
    tm = fmaxf(tm, __shfl_xor(tm, 32, 64));

    u32 pk[4][2];
    float ts = 0.f;
    bool grow = tm > m_run + 8.f;
    if (__any(grow ? 1 : 0)) {
      float newm = fmaxf(m_run, tm);
      float sc = fexp2(m_run - newm);
      m_run = newm;
#pragma unroll
      for (int nf = 0; nf < 4; ++nf) {
        float e0 = fexp2(pvv[nf][0] - newm), e1 = fexp2(pvv[nf][1] - newm);
        float e2 = fexp2(pvv[nf][2] - newm), e3 = fexp2(pvv[nf][3] - newm);
        ts += (e0 + e1) + (e2 + e3);
        pk[nf][0] = (u32)f2h(e0) | ((u32)f2h(e1) << 16);
        pk[nf][1] = (u32)f2h(e2) | ((u32)f2h(e3) << 16);
      }
      lsum = lsum * sc + ts;
      float scq[4];
#pragma unroll
      for (int r = 0; r < 4; ++r) scq[r] = __shfl(sc, g * 4 + r, 64);
#pragma unroll
      for (int nf = 0; nf < 4; ++nf)
#pragma unroll
        for (int r = 0; r < 4; ++r) O[nf][r] *= scq[r];
    } else {
#pragma unroll
      for (int nf = 0; nf < 4; ++nf) {
        float e0 = fexp2(pvv[nf][0] - m_run), e1 = fexp2(pvv[nf][1] - m_run);
        float e2 = fexp2(pvv[nf][2] - m_run), e3 = fexp2(pvv[nf][3] - m_run);
        ts += (e0 + e1) + (e2 + e3);
        pk[nf][0] = (u32)f2h(e0) | ((u32)f2h(e1) << 16);
        pk[nf][1] = (u32)f2h(e2) | ((u32)f2h(e3) << 16);
      }
      lsum += ts;
    }

#pragma unroll
    for (int ks = 0; ks < 2; ++ks) {
      int n0 = 2 * ks, n1 = 2 * ks + 1;
      u32 w0a = (u32)__shfl((int)pk[n0][0], laneA, 64);
      u32 w0b = (u32)__shfl((int)pk[n1][0], laneA, 64);
      u32 w1a = (u32)__shfl((int)pk[n0][1], laneA, 64);
      u32 w1b = (u32)__shfl((int)pk[n1][1], laneA, 64);
      u32 w2a = (u32)__shfl((int)pk[n0][0], laneB, 64);
      u32 w2b = (u32)__shfl((int)pk[n1][0], laneB, 64);
      u32 w3a = (u32)__shfl((int)pk[n0][1], laneB, 64);
      u32 w3b = (u32)__shfl((int)pk[n1][1], laneB, 64);
      union { u32 w[4]; f16x8 v; } ap;
      ap.w[0] = sel ? w0b : w0a;
      ap.w[1] = sel ? w1b : w1a;
      ap.w[2] = sel ? w2b : w2a;
      ap.w[3] = sel ? w3b : w3a;
      int kb = ks * 64 + g * 16;
#pragma unroll
      for (int nf = 0; nf < 4; ++nf) {
        int vr = nf * 16 + lrow;
        f16x8 bv = *(const f16x8*)((const char*)sV + vr * 128 + (kb ^ ((vr & 7) << 4)));
        O[nf] = MFMAH(ap.v, bv, O[nf]);
      }
    }
    __syncthreads();
  }

  lsum += __shfl_xor(lsum, 16, 64);
  lsum += __shfl_xor(lsum, 32, 64);
  float linv[4];
#pragma unroll
  for (int r = 0; r < 4; ++r) linv[r] = 1.0f / __shfl(lsum, g * 4 + r, 64);

#pragma unroll
  for (int r = 0; r < 4; ++r) {
    int trow = b * 512 + q0 + wave * 16 + g * 4 + r;
#pragma unroll
    for (int nf = 0; nf < 4; ++nf) {
      int col = h * 64 + nf * 16 + lrow;
      ctx[(size_t)trow * 1024 + col] = f2h(O[nf][r] * linv[r]);
    }
  }
}

// ---------------- launch ----------------
extern "C" void kernel_launch(void* const* d_in, const int* in_sizes, int n_in,
                              void* d_out, int out_size, void* d_ws, size_t ws_size,
                              hipStream_t stream) {
  const float* x     = (const float*)d_in[0];
  const int*   mask  = (const int*)d_in[1];
  const float* w_dkv = (const float*)d_in[2];
  const float* b_dkv = (const float*)d_in[3];
  const float* w_dq  = (const float*)d_in[4];
  const float* b_dq  = (const float*)d_in[5];
  const float* w_uq  = (const float*)d_in[6];
  const float* b_uq  = (const float*)d_in[7];
  const float* w_uk  = (const float*)d_in[8];
  const float* b_uk  = (const float*)d_in[9];
  const float* w_uv  = (const float*)d_in[10];
  const float* b_uv  = (const float*)d_in[11];
  const float* w_qr  = (const float*)d_in[12];
  const float* b_qr  = (const float*)d_in[13];
  const float* w_kr  = (const float*)d_in[14];
  const float* b_kr  = (const float*)d_in[15];
  const float* w_fc  = (const float*)d_in[16];
  const float* b_fc  = (const float*)d_in[17];
  float* out = (float*)d_out;

  char* ws = (char*)d_ws;
  size_t off = 0;
  auto alloc = [&](size_t bytes) -> void* {
    void* p = ws + off;
    off += (bytes + 255) & ~(size_t)255;
    return p;
  };
  u16* xh     = (u16*)alloc(33554432);   // [8192][2048] f16
  u16* WfT    = (u16*)alloc(4194304);    // [1024][2048] f16
  u16* WqT    = (u16*)alloc(2097152);    // [2048][512]: uq | qr
  u16* WkvT   = (u16*)alloc(2228224);    // [2176][512]: uk | uv | kr(pad 128)
  u16* WfcT   = (u16*)alloc(4194304);    // [2048][1024]
  u16* c      = (u16*)alloc(16777216);   // [8192][1024] f16 (reused as ctx)
  u16* Qb     = (u16*)alloc(33554432);   // [256][512][128] f16
  u16* Kb     = (u16*)alloc(33554432);
  u16* Vt     = (u16*)alloc(16777216);   // [256][64][512] f16
  float2* stab = (float2*)alloc(131072); // [512][32] {sin,cos}
  float* biasQ  = (float*)alloc(8192);
  float* biasKV = (float*)alloc(8704);
  u16* ctx = c;
  (void)ws_size; (void)in_sizes; (void)n_in; (void)out_size;

  const float scale = 1.0f / (sqrtf(128.0f) + sqrtf(64.0f));
  const float scale2 = scale * 1.4426950408889634f;  // log2(e) folded

  prep_kernel<<<81, 256, 0, stream>>>(stab, b_uq, b_qr, b_uk, b_uv, b_kr, biasQ, biasKV);
  convert_x_kernel<<<16384, 256, 0, stream>>>(x, xh, 4194304);
  {
    Wptrs wf{w_dkv, w_dq, nullptr, nullptr};
    wtrans_kernel<<<dim3(64, 16, 2), 256, 0, stream>>>(wf, 512, WfT, 0, 512, 2048);
    Wptrs wq{w_uq, w_qr, nullptr, nullptr};
    wtrans_kernel<<<dim3(16, 32, 2), 256, 0, stream>>>(wq, 1024, WqT, 0, 1024, 512);
    Wptrs wkv{w_uk, w_uv, nullptr, nullptr};
    wtrans_kernel<<<dim3(16, 32, 2), 256, 0, stream>>>(wkv, 1024, WkvT, 0, 1024, 512);
    Wptrs wkr{w_kr, nullptr, nullptr, nullptr};
    wtrans_kernel<<<dim3(16, 2, 1), 256, 0, stream>>>(wkr, 64, WkvT, 2048, 0, 512);
    Wptrs wfc{w_fc, nullptr, nullptr, nullptr};
    wtrans_kernel<<<dim3(32, 64, 1), 256, 0, stream>>>(wfc, 2048, WfcT, 0, 0, 1024);
  }

  // c = x @ [w_dkv | w_dq] + bias  -> f16 [8192][1024], 1-term
  gemmh_kernel<3><<<dim3(64, 8), 256, 0, stream>>>(
      xh, 2048, WfT, 2048, b_dkv, b_dq, 512,
      (void*)c, nullptr, nullptr, 1024, 2048, 1024);
  // q-side fused: [q_c | rope(q_r)] -> Qb
  gemmh_kernel<7><<<dim3(64, 16), 256, 0, stream>>>(
      c + 512, 1024, WqT, 512, biasQ, biasQ, 2048,
      (void*)Qb, nullptr, stab, 2048, 512, 0);
  // kv-side fused: [k_c | v^T | rope(k_r) broadcast] -> Kb, Vt
  gemmh_kernel<6><<<dim3(64, 17), 256, 0, stream>>>(
      c, 1024, WkvT, 512, biasKV, biasKV, 2176,
      (void*)Kb, (void*)Vt, stab, 2176, 512, 0);

  attn_kernel<<<dim3(256, 8), 256, 0, stream>>>(Qb, Kb, Vt, mask, ctx, scale2);

  // out = ctx @ w_fc + b_fc  -> f32 [8192][2048], 1-term
  gemmh_kernel<0><<<dim3(64, 16), 256, 0, stream>>>(
      ctx, 1024, WfcT, 1024, b_fc, b_fc, 2048,
      (void*)out, nullptr, nullptr, 2048, 1024, 2048);
}